// Round 1
// baseline (215.798 us; speedup 1.0000x reference)
//
#include <hip/hip_runtime.h>

typedef __attribute__((ext_vector_type(4))) float f32x4;
typedef __attribute__((ext_vector_type(8))) short short8;

#define DEVI static __device__ __forceinline__

constexpr int B_ = 4;
constexpr int N_ = 4096;
constexpr int H_ = 128;
constexpr int QTILE = 64;      // q rows per block
constexpr int KVSTEP = 128;    // kv rows staged per step
constexpr int KVHALF = 64;     // kv rows per wave-group
constexpr int NTHREADS = 512;  // 8 waves
constexpr int NSTEPS = N_ / KVSTEP;

DEVI unsigned short f2bf(float x) {
  union { float f; unsigned u; } a; a.f = x;
  unsigned u = a.u;
  return (unsigned short)((u + 0x7FFFu + ((u >> 16) & 1u)) >> 16);  // RNE
}

// XOR swizzle: spread D=128 row-major rows across 8 16B slots (guide §6 G4)
DEVI int swz(int byteoff, int row) { return byteoff ^ ((row & 7) << 4); }

__global__ __launch_bounds__(NTHREADS, 2)
void fattn_kernel(const float* __restrict__ q, const float* __restrict__ k,
                  const float* __restrict__ v, float* __restrict__ out) {
  __shared__ unsigned short Klds[KVSTEP * H_];       // [kv][h] bf16, swizzled, 32KB
  __shared__ unsigned short Vtlds[H_ * KVSTEP];      // [h][kv] bf16, swizzled, 32KB
  __shared__ unsigned short Plds[8][16 * KVHALF];    // per-wave P tile, 16KB
  __shared__ float MLlds[4][16][2];                  // merge m/l exchange

  const int tid = threadIdx.x;
  const int wave = tid >> 6;
  const int lane = tid & 63;
  const int l15 = lane & 15;
  const int l4 = lane >> 4;
  const int sub = wave & 3;   // q sub-tile (16 rows)
  const int grp = wave >> 2;  // 0: kv[0:64), 1: kv[64:128) of each step

  const int b = blockIdx.y;
  const int qbase = blockIdx.x * QTILE;

  const float* qp = q + ((size_t)b * N_ + qbase + sub * 16 + l15) * H_;
  const float* kp = k + (size_t)b * N_ * H_;
  const float* vp = v + (size_t)b * N_ * H_;

  // Q fragments in registers, scale = 1/sqrt(H) * log2(e) folded in (exp2 domain)
  const float qscale = 0.08838834764831845f * 1.4426950408889634f;
  short8 qfrag[4];
#pragma unroll
  for (int kc = 0; kc < 4; ++kc) {
    const float4* s = (const float4*)(qp + 8 * l4 + 32 * kc);
    float4 a = s[0], bb = s[1];
    short8 t;
    t[0] = (short)f2bf(a.x * qscale);  t[1] = (short)f2bf(a.y * qscale);
    t[2] = (short)f2bf(a.z * qscale);  t[3] = (short)f2bf(a.w * qscale);
    t[4] = (short)f2bf(bb.x * qscale); t[5] = (short)f2bf(bb.y * qscale);
    t[6] = (short)f2bf(bb.z * qscale); t[7] = (short)f2bf(bb.w * qscale);
    qfrag[kc] = t;
  }

  f32x4 Oacc[8];
#pragma unroll
  for (int i = 0; i < 8; ++i) Oacc[i] = (f32x4){0.f, 0.f, 0.f, 0.f};
  float mrun[4], lrun[4];
#pragma unroll
  for (int r = 0; r < 4; ++r) { mrun[r] = -__builtin_inff(); lrun[r] = 0.f; }

  const int kvbase = grp * KVHALF;

  for (int step = 0; step < NSTEPS; ++step) {
    __syncthreads();  // previous tile fully consumed before overwrite
    // ---- stage K: row-major bf16, coalesced float4 loads, b64 LDS writes ----
    const float4* ks = (const float4*)(kp + (size_t)step * KVSTEP * H_);
#pragma unroll
    for (int i = 0; i < 8; ++i) {
      int f = tid + NTHREADS * i;   // float4 index 0..4095
      int row = f >> 5, c4 = f & 31;
      float4 val = ks[f];
      uint2 pk;
      pk.x = (unsigned)f2bf(val.x) | ((unsigned)f2bf(val.y) << 16);
      pk.y = (unsigned)f2bf(val.z) | ((unsigned)f2bf(val.w) << 16);
      *(uint2*)((char*)Klds + swz(row * 256 + c4 * 8, row)) = pk;
    }
    // ---- stage V transposed: [h][kv], lane-kv-diverse to avoid bank conflicts ----
    const float4* vs = (const float4*)(vp + (size_t)step * KVSTEP * H_);
    {
      int c4 = tid >> 4, prb = tid & 15;
#pragma unroll
      for (int i = 0; i < 4; ++i) {
        int pr = prb + 16 * i;      // kv row-pair 0..63
        float4 v0 = vs[(2 * pr) * 32 + c4];
        float4 v1 = vs[(2 * pr + 1) * 32 + c4];
        float a0[4] = {v0.x, v0.y, v0.z, v0.w};
        float a1[4] = {v1.x, v1.y, v1.z, v1.w};
#pragma unroll
        for (int j = 0; j < 4; ++j) {
          int col = 4 * c4 + j;     // h
          unsigned pk = (unsigned)f2bf(a0[j]) | ((unsigned)f2bf(a1[j]) << 16);
          *(unsigned*)((char*)Vtlds + swz(col * 256 + pr * 4, col)) = pk;
        }
      }
    }
    __syncthreads();

    // ---- QK^T: S[16 q][64 kv], A=Q(regs), B=K rows (same frag pattern) ----
    f32x4 S[4];
#pragma unroll
    for (int ct = 0; ct < 4; ++ct) S[ct] = (f32x4){0.f, 0.f, 0.f, 0.f};
#pragma unroll
    for (int ct = 0; ct < 4; ++ct) {
      int kvrow = kvbase + ct * 16 + l15;
#pragma unroll
      for (int kc = 0; kc < 4; ++kc) {
        short8 bfrag = *(const short8*)((const char*)Klds +
            swz(kvrow * 256 + (8 * l4 + 32 * kc) * 2, kvrow));
        S[ct] = __builtin_amdgcn_mfma_f32_16x16x32_bf16(qfrag[kc], bfrag, S[ct], 0, 0, 0);
      }
    }

    // ---- online softmax (exp2 domain); D-layout row = 4*l4+r, col = l15+16*ct ----
    float mnew[4];
#pragma unroll
    for (int r = 0; r < 4; ++r) {
      float mx = fmaxf(fmaxf(S[0][r], S[1][r]), fmaxf(S[2][r], S[3][r]));
      mx = fmaxf(mx, __shfl_xor(mx, 1));
      mx = fmaxf(mx, __shfl_xor(mx, 2));
      mx = fmaxf(mx, __shfl_xor(mx, 4));
      mx = fmaxf(mx, __shfl_xor(mx, 8));
      mnew[r] = mx;
    }
    float alpha[4];
#pragma unroll
    for (int r = 0; r < 4; ++r) {
      float mi = fmaxf(mrun[r], mnew[r]);
      alpha[r] = __builtin_amdgcn_exp2f(mrun[r] - mi);
      mrun[r] = mi;
    }
    float rsum[4] = {0.f, 0.f, 0.f, 0.f};
    unsigned short pb[4][4];
#pragma unroll
    for (int ct = 0; ct < 4; ++ct)
#pragma unroll
      for (int r = 0; r < 4; ++r) {
        float pv = __builtin_amdgcn_exp2f(S[ct][r] - mrun[r]);
        rsum[r] += pv;
        pb[ct][r] = f2bf(pv);
      }
#pragma unroll
    for (int r = 0; r < 4; ++r) {
      float s = rsum[r];
      s += __shfl_xor(s, 1); s += __shfl_xor(s, 2);
      s += __shfl_xor(s, 4); s += __shfl_xor(s, 8);
      lrun[r] = lrun[r] * alpha[r] + s;
    }
#pragma unroll
    for (int ct2 = 0; ct2 < 8; ++ct2)
#pragma unroll
      for (int r = 0; r < 4; ++r) Oacc[ct2][r] *= alpha[r];

    // ---- P (D-layout) -> LDS -> A-layout (wave-private, no barrier needed) ----
    char* pbase = (char*)Plds[wave];
#pragma unroll
    for (int ct = 0; ct < 4; ++ct)
#pragma unroll
      for (int r = 0; r < 4; ++r) {
        int qrow = 4 * l4 + r;
        int kv = l15 + 16 * ct;
        *(unsigned short*)(pbase + swz(qrow * 128 + kv * 2, qrow)) = pb[ct][r];
      }

    // ---- PV: O[16 q][128 h] += P[16][64] * V[64][128] ----
#pragma unroll
    for (int kc2 = 0; kc2 < 2; ++kc2) {
      short8 afrag = *(const short8*)(pbase +
          swz(l15 * 128 + (8 * l4 + 32 * kc2) * 2, l15));
#pragma unroll
      for (int ct2 = 0; ct2 < 8; ++ct2) {
        int h = l15 + 16 * ct2;
        short8 bfrag = *(const short8*)((const char*)Vtlds +
            swz(h * 256 + (kvbase + 8 * l4 + 32 * kc2) * 2, h));
        Oacc[ct2] = __builtin_amdgcn_mfma_f32_16x16x32_bf16(afrag, bfrag, Oacc[ct2], 0, 0, 0);
      }
    }
  }

  // ---- merge the two kv-half partials (flash combine), then write out ----
  __syncthreads();
  float* mergeO = (float*)Klds;  // reuse 32KB: [sub][16][128] f32
  if (grp == 1) {
#pragma unroll
    for (int ct2 = 0; ct2 < 8; ++ct2)
#pragma unroll
      for (int r = 0; r < 4; ++r) {
        int qrow = 4 * l4 + r, h = l15 + 16 * ct2;
        mergeO[(sub * 16 + qrow) * H_ + h] = Oacc[ct2][r];
      }
    if (l15 == 0) {
#pragma unroll
      for (int r = 0; r < 4; ++r) {
        int qrow = 4 * l4 + r;
        MLlds[sub][qrow][0] = mrun[r];
        MLlds[sub][qrow][1] = lrun[r];
      }
    }
  }
  __syncthreads();
  if (grp == 0) {
    float aA[4], aB[4], rl[4];
#pragma unroll
    for (int r = 0; r < 4; ++r) {
      int qrow = 4 * l4 + r;
      float mB = MLlds[sub][qrow][0], lB = MLlds[sub][qrow][1];
      float mi = fmaxf(mrun[r], mB);
      aA[r] = __builtin_amdgcn_exp2f(mrun[r] - mi);
      aB[r] = __builtin_amdgcn_exp2f(mB - mi);
      rl[r] = 1.f / (lrun[r] * aA[r] + lB * aB[r]);
    }
    float* outp = out + ((size_t)b * N_ + qbase + sub * 16) * H_;
#pragma unroll
    for (int ct2 = 0; ct2 < 8; ++ct2)
#pragma unroll
      for (int r = 0; r < 4; ++r) {
        int qrow = 4 * l4 + r, h = l15 + 16 * ct2;
        float ob = mergeO[(sub * 16 + qrow) * H_ + h];
        outp[(size_t)qrow * H_ + h] = (Oacc[ct2][r] * aA[r] + ob * aB[r]) * rl[r];
      }
  }
}

extern "C" void kernel_launch(void* const* d_in, const int* in_sizes, int n_in,
                              void* d_out, int out_size, void* d_ws, size_t ws_size,
                              hipStream_t stream) {
  const float* q = (const float*)d_in[0];
  const float* k = (const float*)d_in[1];
  const float* v = (const float*)d_in[2];
  float* out = (float*)d_out;
  dim3 grid(N_ / QTILE, B_);
  fattn_kernel<<<grid, dim3(NTHREADS), 0, stream>>>(q, k, v, out);
}

// Round 2
// 103.377 us; speedup vs baseline: 2.0875x; 2.0875x over previous
//
#include <hip/hip_runtime.h>

typedef __attribute__((ext_vector_type(4))) float f32x4;
typedef __attribute__((ext_vector_type(8))) short short8;

#define DEVI static __device__ __forceinline__

constexpr int B_ = 4;
constexpr int N_ = 4096;
constexpr int H_ = 128;
constexpr int QTILE = 64;      // q rows per block
constexpr int KVSTEP = 128;    // kv rows staged per step
constexpr int KVHALF = 64;     // kv rows per wave-group
constexpr int NTHREADS = 512;  // 8 waves
constexpr int NSTEPS = N_ / KVSTEP;
constexpr size_t ELEMS = (size_t)B_ * N_ * H_;   // per tensor
constexpr size_t TSB = ELEMS * 2;                // bf16 bytes per tensor

DEVI unsigned short f2bf(float x) {
  union { float f; unsigned u; } a; a.f = x;
  unsigned u = a.u;
  return (unsigned short)((u + 0x7FFFu + ((u >> 16) & 1u)) >> 16);  // RNE
}

// XOR swizzle: spread D=128 row-major rows across 8 16B slots (guide §6 G4)
DEVI int swz(int byteoff, int row) { return byteoff ^ ((row & 7) << 4); }

DEVI void gl_lds16(const void* g, void* l) {
  __builtin_amdgcn_global_load_lds(
      (const __attribute__((address_space(1))) void*)g,
      (__attribute__((address_space(3))) void*)l, 16, 0, 0);
}

// ---------------- pre-pass: convert Q(scaled)/K to bf16 ----------------
__global__ void conv_qk(const float* __restrict__ q, const float* __restrict__ k,
                        unsigned short* __restrict__ qb, unsigned short* __restrict__ kb) {
  const float qscale = 0.08838834764831845f * 1.4426950408889634f;  // 1/sqrt(H)*log2e
  size_t i = (size_t)blockIdx.x * blockDim.x + threadIdx.x;  // vec8 index
  {
    const float4* s = (const float4*)q + 2 * i;
    float4 a = s[0], b = s[1];
    short8 t;
    t[0] = (short)f2bf(a.x * qscale); t[1] = (short)f2bf(a.y * qscale);
    t[2] = (short)f2bf(a.z * qscale); t[3] = (short)f2bf(a.w * qscale);
    t[4] = (short)f2bf(b.x * qscale); t[5] = (short)f2bf(b.y * qscale);
    t[6] = (short)f2bf(b.z * qscale); t[7] = (short)f2bf(b.w * qscale);
    *(short8*)(qb + i * 8) = t;
  }
  {
    const float4* s = (const float4*)k + 2 * i;
    float4 a = s[0], b = s[1];
    short8 t;
    t[0] = (short)f2bf(a.x); t[1] = (short)f2bf(a.y);
    t[2] = (short)f2bf(a.z); t[3] = (short)f2bf(a.w);
    t[4] = (short)f2bf(b.x); t[5] = (short)f2bf(b.y);
    t[6] = (short)f2bf(b.z); t[7] = (short)f2bf(b.w);
    *(short8*)(kb + i * 8) = t;
  }
}

// ---------------- pre-pass: V -> V^T bf16 ([b][h][n]) ----------------
__global__ void conv_vt(const float* __restrict__ v, unsigned short* __restrict__ vt) {
  __shared__ unsigned short T[64][72];  // padded, 16B-aligned rows (144B)
  const int n0 = blockIdx.x * 64, h0 = blockIdx.y * 64, b = blockIdx.z;
  const int t = threadIdx.x;
  const int c4 = t & 15, r = t >> 4;
#pragma unroll
  for (int i = 0; i < 4; ++i) {
    int n = n0 + r + 16 * i;
    float4 val = *(const float4*)(v + ((size_t)b * N_ + n) * H_ + h0 + 4 * c4);
    T[4 * c4 + 0][r + 16 * i] = f2bf(val.x);
    T[4 * c4 + 1][r + 16 * i] = f2bf(val.y);
    T[4 * c4 + 2][r + 16 * i] = f2bf(val.z);
    T[4 * c4 + 3][r + 16 * i] = f2bf(val.w);
  }
  __syncthreads();
  const int c8 = t & 7, hr = t >> 3;
#pragma unroll
  for (int i = 0; i < 2; ++i) {
    int hl = hr + 32 * i;
    short8 val = *(const short8*)(&T[hl][8 * c8]);
    *(short8*)(vt + ((size_t)b * H_ + h0 + hl) * N_ + n0 + 8 * c8) = val;
  }
}

// ---------------- main: flash attention, double-buffered gload_lds ----------------
__global__ __launch_bounds__(NTHREADS, 2)
void fattn_fast(const unsigned short* __restrict__ qws,
                const unsigned short* __restrict__ kws,
                const unsigned short* __restrict__ vtws,
                float* __restrict__ out) {
  __shared__ unsigned short Kbuf[2][KVSTEP * H_];   // [kv][h] swizzled, 2x32KB
  __shared__ unsigned short Vbuf[2][H_ * KVSTEP];   // [h][kv] swizzled, 2x32KB
  __shared__ unsigned short Plds[8][16 * KVHALF];   // per-wave P tile, 16KB
  __shared__ float MLlds[4][16][2];

  const int tid = threadIdx.x;
  const int wave = tid >> 6;
  const int lane = tid & 63;
  const int l15 = lane & 15;
  const int l4 = lane >> 4;
  const int sub = wave & 3;   // q sub-tile (16 rows)
  const int grp = wave >> 2;  // kv half

  const int b = blockIdx.y;
  const int qbase = blockIdx.x * QTILE;

  // Q fragments straight from pre-scaled bf16
  const unsigned short* qp = qws + ((size_t)b * N_ + qbase + sub * 16 + l15) * H_;
  short8 qfrag[4];
#pragma unroll
  for (int kc = 0; kc < 4; ++kc)
    qfrag[kc] = *(const short8*)(qp + 8 * l4 + 32 * kc);

  f32x4 Oacc[8];
#pragma unroll
  for (int i = 0; i < 8; ++i) Oacc[i] = (f32x4){0.f, 0.f, 0.f, 0.f};
  float mrun[4], lrun[4];
#pragma unroll
  for (int r = 0; r < 4; ++r) { mrun[r] = -__builtin_inff(); lrun[r] = 0.f; }

  const char* kbase = (const char*)(kws + (size_t)b * N_ * H_);
  const char* vbase = (const char*)(vtws + (size_t)b * H_ * N_);
  const int kvbase = grp * KVHALF;
  char* pbase = (char*)Plds[wave];

  // stage one 128-row K/V tile into buf; pre-swizzled global source, linear LDS dest
  auto stage = [&](int buf, int step) {
    const char* ktile = kbase + (size_t)step * KVSTEP * H_ * 2;  // 32KB contiguous
#pragma unroll
    for (int i = 0; i < 4; ++i) {
      int chunk = wave * 4 + i;                 // 32 chunks x 1KB
      int off = chunk * 1024 + lane * 16;
      int row = off >> 8, col = off & 255;
      gl_lds16(ktile + row * 256 + (col ^ ((row & 7) << 4)),
               (char*)Kbuf[buf] + chunk * 1024);
    }
#pragma unroll
    for (int i = 0; i < 4; ++i) {
      int chunk = wave * 4 + i;                 // 4 h-rows per chunk
      int h = chunk * 4 + (lane >> 4);
      int colb = (lane & 15) * 16;
      gl_lds16(vbase + (size_t)h * (N_ * 2) + (size_t)step * 256 + (colb ^ ((h & 7) << 4)),
               (char*)Vbuf[buf] + chunk * 1024);
    }
  };

  int cur = 0;
  stage(0, 0);
  __syncthreads();

  for (int step = 0; step < NSTEPS; ++step) {
    if (step + 1 < NSTEPS) stage(cur ^ 1, step + 1);  // prefetch next tile

    const char* Kl = (const char*)Kbuf[cur];
    const char* Vl = (const char*)Vbuf[cur];

    // ---- QK^T: S[16 q][64 kv] ----
    f32x4 S[4];
#pragma unroll
    for (int ct = 0; ct < 4; ++ct) S[ct] = (f32x4){0.f, 0.f, 0.f, 0.f};
#pragma unroll
    for (int ct = 0; ct < 4; ++ct) {
      int kvrow = kvbase + ct * 16 + l15;
#pragma unroll
      for (int kc = 0; kc < 4; ++kc) {
        short8 bfrag = *(const short8*)(Kl +
            swz(kvrow * 256 + (8 * l4 + 32 * kc) * 2, kvrow));
        S[ct] = __builtin_amdgcn_mfma_f32_16x16x32_bf16(qfrag[kc], bfrag, S[ct], 0, 0, 0);
      }
    }

    // ---- online softmax (exp2 domain); D-layout row = 4*l4+r, col = l15+16*ct ----
    float mnew[4];
#pragma unroll
    for (int r = 0; r < 4; ++r) {
      float mx = fmaxf(fmaxf(S[0][r], S[1][r]), fmaxf(S[2][r], S[3][r]));
      mx = fmaxf(mx, __shfl_xor(mx, 1));
      mx = fmaxf(mx, __shfl_xor(mx, 2));
      mx = fmaxf(mx, __shfl_xor(mx, 4));
      mx = fmaxf(mx, __shfl_xor(mx, 8));
      mnew[r] = mx;
    }
    float alpha[4];
#pragma unroll
    for (int r = 0; r < 4; ++r) {
      float mi = fmaxf(mrun[r], mnew[r]);
      alpha[r] = __builtin_amdgcn_exp2f(mrun[r] - mi);
      mrun[r] = mi;
    }
    float rsum[4] = {0.f, 0.f, 0.f, 0.f};
    unsigned short pb[4][4];
#pragma unroll
    for (int ct = 0; ct < 4; ++ct)
#pragma unroll
      for (int r = 0; r < 4; ++r) {
        float pv = __builtin_amdgcn_exp2f(S[ct][r] - mrun[r]);
        rsum[r] += pv;
        pb[ct][r] = f2bf(pv);
      }
#pragma unroll
    for (int r = 0; r < 4; ++r) {
      float s = rsum[r];
      s += __shfl_xor(s, 1); s += __shfl_xor(s, 2);
      s += __shfl_xor(s, 4); s += __shfl_xor(s, 8);
      lrun[r] = lrun[r] * alpha[r] + s;
    }
#pragma unroll
    for (int ct2 = 0; ct2 < 8; ++ct2)
#pragma unroll
      for (int r = 0; r < 4; ++r) Oacc[ct2][r] *= alpha[r];

    // ---- P (D-layout) -> LDS -> A-layout (wave-private) ----
#pragma unroll
    for (int ct = 0; ct < 4; ++ct)
#pragma unroll
      for (int r = 0; r < 4; ++r) {
        int qrow = 4 * l4 + r;
        int kv = l15 + 16 * ct;
        *(unsigned short*)(pbase + swz(qrow * 128 + kv * 2, qrow)) = pb[ct][r];
      }

    // ---- PV: O[16 q][128 h] += P[16][64] * V[64][128] ----
#pragma unroll
    for (int kc2 = 0; kc2 < 2; ++kc2) {
      short8 afrag = *(const short8*)(pbase +
          swz(l15 * 128 + (8 * l4 + 32 * kc2) * 2, l15));
#pragma unroll
      for (int ct2 = 0; ct2 < 8; ++ct2) {
        int h = l15 + 16 * ct2;
        short8 bfrag = *(const short8*)(Vl +
            swz(h * 256 + (kvbase + 8 * l4 + 32 * kc2) * 2, h));
        Oacc[ct2] = __builtin_amdgcn_mfma_f32_16x16x32_bf16(afrag, bfrag, Oacc[ct2], 0, 0, 0);
      }
    }

    __syncthreads();   // drains vmcnt (prefetch done) + all waves done with buf[cur]
    cur ^= 1;
  }

  // ---- merge the two kv-half partials, write out ----
  float* mergeO = (float*)Kbuf;  // reuse 64KB: need [4][16][128] f32 = 32KB
  if (grp == 1) {
#pragma unroll
    for (int ct2 = 0; ct2 < 8; ++ct2)
#pragma unroll
      for (int r = 0; r < 4; ++r) {
        int qrow = 4 * l4 + r, h = l15 + 16 * ct2;
        mergeO[(sub * 16 + qrow) * H_ + h] = Oacc[ct2][r];
      }
    if (l15 == 0) {
#pragma unroll
      for (int r = 0; r < 4; ++r) {
        int qrow = 4 * l4 + r;
        MLlds[sub][qrow][0] = mrun[r];
        MLlds[sub][qrow][1] = lrun[r];
      }
    }
  }
  __syncthreads();
  if (grp == 0) {
    float aA[4], aB[4], rl[4];
#pragma unroll
    for (int r = 0; r < 4; ++r) {
      int qrow = 4 * l4 + r;
      float mB = MLlds[sub][qrow][0], lB = MLlds[sub][qrow][1];
      float mi = fmaxf(mrun[r], mB);
      aA[r] = __builtin_amdgcn_exp2f(mrun[r] - mi);
      aB[r] = __builtin_amdgcn_exp2f(mB - mi);
      rl[r] = 1.f / (lrun[r] * aA[r] + lB * aB[r]);
    }
    float* outp = out + ((size_t)b * N_ + qbase + sub * 16) * H_;
#pragma unroll
    for (int ct2 = 0; ct2 < 8; ++ct2)
#pragma unroll
      for (int r = 0; r < 4; ++r) {
        int qrow = 4 * l4 + r, h = l15 + 16 * ct2;
        float ob = mergeO[(sub * 16 + qrow) * H_ + h];
        outp[(size_t)qrow * H_ + h] = (Oacc[ct2][r] * aA[r] + ob * aB[r]) * rl[r];
      }
  }
}

// ---------------- fallback (R1 kernel, used only if ws too small) ----------------
__global__ __launch_bounds__(NTHREADS, 2)
void fattn_fallback(const float* __restrict__ q, const float* __restrict__ k,
                    const float* __restrict__ v, float* __restrict__ out) {
  __shared__ unsigned short Klds[KVSTEP * H_];
  __shared__ unsigned short Vtlds[H_ * KVSTEP];
  __shared__ unsigned short Plds[8][16 * KVHALF];
  __shared__ float MLlds[4][16][2];

  const int tid = threadIdx.x;
  const int wave = tid >> 6;
  const int lane = tid & 63;
  const int l15 = lane & 15;
  const int l4 = lane >> 4;
  const int sub = wave & 3;
  const int grp = wave >> 2;

  const int b = blockIdx.y;
  const int qbase = blockIdx.x * QTILE;

  const float* qp = q + ((size_t)b * N_ + qbase + sub * 16 + l15) * H_;
  const float* kp = k + (size_t)b * N_ * H_;
  const float* vp = v + (size_t)b * N_ * H_;

  const float qscale = 0.08838834764831845f * 1.4426950408889634f;
  short8 qfrag[4];
#pragma unroll
  for (int kc = 0; kc < 4; ++kc) {
    const float4* s = (const float4*)(qp + 8 * l4 + 32 * kc);
    float4 a = s[0], bb = s[1];
    short8 t;
    t[0] = (short)f2bf(a.x * qscale);  t[1] = (short)f2bf(a.y * qscale);
    t[2] = (short)f2bf(a.z * qscale);  t[3] = (short)f2bf(a.w * qscale);
    t[4] = (short)f2bf(bb.x * qscale); t[5] = (short)f2bf(bb.y * qscale);
    t[6] = (short)f2bf(bb.z * qscale); t[7] = (short)f2bf(bb.w * qscale);
    qfrag[kc] = t;
  }

  f32x4 Oacc[8];
#pragma unroll
  for (int i = 0; i < 8; ++i) Oacc[i] = (f32x4){0.f, 0.f, 0.f, 0.f};
  float mrun[4], lrun[4];
#pragma unroll
  for (int r = 0; r < 4; ++r) { mrun[r] = -__builtin_inff(); lrun[r] = 0.f; }

  const int kvbase = grp * KVHALF;

  for (int step = 0; step < NSTEPS; ++step) {
    __syncthreads();
    const float4* ks = (const float4*)(kp + (size_t)step * KVSTEP * H_);
#pragma unroll
    for (int i = 0; i < 8; ++i) {
      int f = tid + NTHREADS * i;
      int row = f >> 5, c4 = f & 31;
      float4 val = ks[f];
      uint2 pk;
      pk.x = (unsigned)f2bf(val.x) | ((unsigned)f2bf(val.y) << 16);
      pk.y = (unsigned)f2bf(val.z) | ((unsigned)f2bf(val.w) << 16);
      *(uint2*)((char*)Klds + swz(row * 256 + c4 * 8, row)) = pk;
    }
    const float4* vs = (const float4*)(vp + (size_t)step * KVSTEP * H_);
    {
      int c4 = tid >> 4, prb = tid & 15;
#pragma unroll
      for (int i = 0; i < 4; ++i) {
        int pr = prb + 16 * i;
        float4 v0 = vs[(2 * pr) * 32 + c4];
        float4 v1 = vs[(2 * pr + 1) * 32 + c4];
        float a0[4] = {v0.x, v0.y, v0.z, v0.w};
        float a1[4] = {v1.x, v1.y, v1.z, v1.w};
#pragma unroll
        for (int j = 0; j < 4; ++j) {
          int col = 4 * c4 + j;
          unsigned pk = (unsigned)f2bf(a0[j]) | ((unsigned)f2bf(a1[j]) << 16);
          *(unsigned*)((char*)Vtlds + swz(col * 256 + pr * 4, col)) = pk;
        }
      }
    }
    __syncthreads();

    f32x4 S[4];
#pragma unroll
    for (int ct = 0; ct < 4; ++ct) S[ct] = (f32x4){0.f, 0.f, 0.f, 0.f};
#pragma unroll
    for (int ct = 0; ct < 4; ++ct) {
      int kvrow = kvbase + ct * 16 + l15;
#pragma unroll
      for (int kc = 0; kc < 4; ++kc) {
        short8 bfrag = *(const short8*)((const char*)Klds +
            swz(kvrow * 256 + (8 * l4 + 32 * kc) * 2, kvrow));
        S[ct] = __builtin_amdgcn_mfma_f32_16x16x32_bf16(qfrag[kc], bfrag, S[ct], 0, 0, 0);
      }
    }

    float mnew[4];
#pragma unroll
    for (int r = 0; r < 4; ++r) {
      float mx = fmaxf(fmaxf(S[0][r], S[1][r]), fmaxf(S[2][r], S[3][r]));
      mx = fmaxf(mx, __shfl_xor(mx, 1));
      mx = fmaxf(mx, __shfl_xor(mx, 2));
      mx = fmaxf(mx, __shfl_xor(mx, 4));
      mx = fmaxf(mx, __shfl_xor(mx, 8));
      mnew[r] = mx;
    }
    float alpha[4];
#pragma unroll
    for (int r = 0; r < 4; ++r) {
      float mi = fmaxf(mrun[r], mnew[r]);
      alpha[r] = __builtin_amdgcn_exp2f(mrun[r] - mi);
      mrun[r] = mi;
    }
    float rsum[4] = {0.f, 0.f, 0.f, 0.f};
    unsigned short pb[4][4];
#pragma unroll
    for (int ct = 0; ct < 4; ++ct)
#pragma unroll
      for (int r = 0; r < 4; ++r) {
        float pv = __builtin_amdgcn_exp2f(S[ct][r] - mrun[r]);
        rsum[r] += pv;
        pb[ct][r] = f2bf(pv);
      }
#pragma unroll
    for (int r = 0; r < 4; ++r) {
      float s = rsum[r];
      s += __shfl_xor(s, 1); s += __shfl_xor(s, 2);
      s += __shfl_xor(s, 4); s += __shfl_xor(s, 8);
      lrun[r] = lrun[r] * alpha[r] + s;
    }
#pragma unroll
    for (int ct2 = 0; ct2 < 8; ++ct2)
#pragma unroll
      for (int r = 0; r < 4; ++r) Oacc[ct2][r] *= alpha[r];

    char* pbase = (char*)Plds[wave];
#pragma unroll
    for (int ct = 0; ct < 4; ++ct)
#pragma unroll
      for (int r = 0; r < 4; ++r) {
        int qrow = 4 * l4 + r;
        int kv = l15 + 16 * ct;
        *(unsigned short*)(pbase + swz(qrow * 128 + kv * 2, qrow)) = pb[ct][r];
      }

#pragma unroll
    for (int kc2 = 0; kc2 < 2; ++kc2) {
      short8 afrag = *(const short8*)(pbase +
          swz(l15 * 128 + (8 * l4 + 32 * kc2) * 2, l15));
#pragma unroll
      for (int ct2 = 0; ct2 < 8; ++ct2) {
        int h = l15 + 16 * ct2;
        short8 bfrag = *(const short8*)((const char*)Vtlds +
            swz(h * 256 + (kvbase + 8 * l4 + 32 * kc2) * 2, h));
        Oacc[ct2] = __builtin_amdgcn_mfma_f32_16x16x32_bf16(afrag, bfrag, Oacc[ct2], 0, 0, 0);
      }
    }
  }

  __syncthreads();
  float* mergeO = (float*)Klds;
  if (grp == 1) {
#pragma unroll
    for (int ct2 = 0; ct2 < 8; ++ct2)
#pragma unroll
      for (int r = 0; r < 4; ++r) {
        int qrow = 4 * l4 + r, h = l15 + 16 * ct2;
        mergeO[(sub * 16 + qrow) * H_ + h] = Oacc[ct2][r];
      }
    if (l15 == 0) {
#pragma unroll
      for (int r = 0; r < 4; ++r) {
        int qrow = 4 * l4 + r;
        MLlds[sub][qrow][0] = mrun[r];
        MLlds[sub][qrow][1] = lrun[r];
      }
    }
  }
  __syncthreads();
  if (grp == 0) {
    float aA[4], aB[4], rl[4];
#pragma unroll
    for (int r = 0; r < 4; ++r) {
      int qrow = 4 * l4 + r;
      float mB = MLlds[sub][qrow][0], lB = MLlds[sub][qrow][1];
      float mi = fmaxf(mrun[r], mB);
      aA[r] = __builtin_amdgcn_exp2f(mrun[r] - mi);
      aB[r] = __builtin_amdgcn_exp2f(mB - mi);
      rl[r] = 1.f / (lrun[r] * aA[r] + lB * aB[r]);
    }
    float* outp = out + ((size_t)b * N_ + qbase + sub * 16) * H_;
#pragma unroll
    for (int ct2 = 0; ct2 < 8; ++ct2)
#pragma unroll
      for (int r = 0; r < 4; ++r) {
        int qrow = 4 * l4 + r, h = l15 + 16 * ct2;
        float ob = mergeO[(sub * 16 + qrow) * H_ + h];
        outp[(size_t)qrow * H_ + h] = (Oacc[ct2][r] * aA[r] + ob * aB[r]) * rl[r];
      }
  }
}

extern "C" void kernel_launch(void* const* d_in, const int* in_sizes, int n_in,
                              void* d_out, int out_size, void* d_ws, size_t ws_size,
                              hipStream_t stream) {
  const float* q = (const float*)d_in[0];
  const float* k = (const float*)d_in[1];
  const float* v = (const float*)d_in[2];
  float* out = (float*)d_out;
  if (ws_size >= 3 * TSB) {
    unsigned short* qb = (unsigned short*)d_ws;
    unsigned short* kb = qb + ELEMS;
    unsigned short* vt = kb + ELEMS;
    conv_qk<<<dim3((unsigned)(ELEMS / 8 / 256)), dim3(256), 0, stream>>>(q, k, qb, kb);
    conv_vt<<<dim3(N_ / 64, H_ / 64, B_), dim3(256), 0, stream>>>(v, vt);
    fattn_fast<<<dim3(N_ / QTILE, B_), dim3(NTHREADS), 0, stream>>>(qb, kb, vt, out);
  } else {
    fattn_fallback<<<dim3(N_ / QTILE, B_), dim3(NTHREADS), 0, stream>>>(q, k, v, out);
  }
}

// Round 3
// 85.264 us; speedup vs baseline: 2.5309x; 1.2124x over previous
//
#include <hip/hip_runtime.h>

typedef __attribute__((ext_vector_type(4))) float f32x4;
typedef __attribute__((ext_vector_type(8))) short short8;

#define DEVI static __device__ __forceinline__

constexpr int B_ = 4;
constexpr int N_ = 4096;
constexpr int H_ = 128;
constexpr size_t ELEMS = (size_t)B_ * N_ * H_;   // per tensor
constexpr size_t TSB = ELEMS * 2;                // bf16 bytes per tensor

// ---- v3 geometry ----
constexpr int QT = 128;                 // q rows per block (4 waves x 32)
constexpr int KSPLIT = 2;               // kv split across grid.z
constexpr int KVRANGE = N_ / KSPLIT;    // 2048 kv rows per block
constexpr int KVB = 64;                 // kv rows per step
constexpr int NST = KVRANGE / KVB;      // 32 steps
constexpr int NTH = 256;                // 4 waves

DEVI unsigned short f2bf(float x) {
  union { float f; unsigned u; } a; a.f = x;
  unsigned u = a.u;
  return (unsigned short)((u + 0x7FFFu + ((u >> 16) & 1u)) >> 16);  // RNE
}

DEVI int swz(int byteoff, int row) { return byteoff ^ ((row & 7) << 4); }

DEVI void gl_lds16(const void* g, void* l) {
  __builtin_amdgcn_global_load_lds(
      (const __attribute__((address_space(1))) void*)g,
      (__attribute__((address_space(3))) void*)l, 16, 0, 0);
}

// ---------------- pre-pass: convert Q(scaled)/K to bf16 ----------------
__global__ void conv_qk(const float* __restrict__ q, const float* __restrict__ k,
                        unsigned short* __restrict__ qb, unsigned short* __restrict__ kb) {
  const float qscale = 0.08838834764831845f * 1.4426950408889634f;  // 1/sqrt(H)*log2e
  size_t i = (size_t)blockIdx.x * blockDim.x + threadIdx.x;  // vec8 index
  {
    const float4* s = (const float4*)q + 2 * i;
    float4 a = s[0], b = s[1];
    short8 t;
    t[0] = (short)f2bf(a.x * qscale); t[1] = (short)f2bf(a.y * qscale);
    t[2] = (short)f2bf(a.z * qscale); t[3] = (short)f2bf(a.w * qscale);
    t[4] = (short)f2bf(b.x * qscale); t[5] = (short)f2bf(b.y * qscale);
    t[6] = (short)f2bf(b.z * qscale); t[7] = (short)f2bf(b.w * qscale);
    *(short8*)(qb + i * 8) = t;
  }
  {
    const float4* s = (const float4*)k + 2 * i;
    float4 a = s[0], b = s[1];
    short8 t;
    t[0] = (short)f2bf(a.x); t[1] = (short)f2bf(a.y);
    t[2] = (short)f2bf(a.z); t[3] = (short)f2bf(a.w);
    t[4] = (short)f2bf(b.x); t[5] = (short)f2bf(b.y);
    t[6] = (short)f2bf(b.z); t[7] = (short)f2bf(b.w);
    *(short8*)(kb + i * 8) = t;
  }
}

// ---------------- pre-pass: V -> V^T bf16 ([b][h][n]) ----------------
__global__ void conv_vt(const float* __restrict__ v, unsigned short* __restrict__ vt) {
  __shared__ unsigned short T[64][72];
  const int n0 = blockIdx.x * 64, h0 = blockIdx.y * 64, b = blockIdx.z;
  const int t = threadIdx.x;
  const int c4 = t & 15, r = t >> 4;
#pragma unroll
  for (int i = 0; i < 4; ++i) {
    int n = n0 + r + 16 * i;
    float4 val = *(const float4*)(v + ((size_t)b * N_ + n) * H_ + h0 + 4 * c4);
    T[4 * c4 + 0][r + 16 * i] = f2bf(val.x);
    T[4 * c4 + 1][r + 16 * i] = f2bf(val.y);
    T[4 * c4 + 2][r + 16 * i] = f2bf(val.z);
    T[4 * c4 + 3][r + 16 * i] = f2bf(val.w);
  }
  __syncthreads();
  const int c8 = t & 7, hr = t >> 3;
#pragma unroll
  for (int i = 0; i < 2; ++i) {
    int hl = hr + 32 * i;
    short8 val = *(const short8*)(&T[hl][8 * c8]);
    *(short8*)(vt + ((size_t)b * H_ + h0 + hl) * N_ + n0 + 8 * c8) = val;
  }
}

// ---------------- main v3: swapped-operand flash attention ----------------
// Each wave owns 32 q rows (two 16-col tiles). S^T = mfma(K,Q): lane's q = lane&15,
// kv = 16*ct + 4*(lane>>4) + r. O^T = mfma(V^T, P^T): lane's q = lane&15, h per reg.
__global__ __launch_bounds__(NTH, 2)
void fattn_v3(const unsigned short* __restrict__ qws,
              const unsigned short* __restrict__ kws,
              const unsigned short* __restrict__ vtws,
              float* __restrict__ opart, float* __restrict__ mlpart) {
  __shared__ __align__(16) char smem[73728];
  char* Kb0 = smem;             // 16KB x2 (double buffer)
  char* Vb0 = smem + 32768;     // 16KB x2
  // P: per-wave 2KB at smem + 65536 + wave*2048

  const int tid = threadIdx.x, wave = tid >> 6, lane = tid & 63;
  const int l15 = lane & 15, l4 = lane >> 4;
  const int b = blockIdx.y, z = blockIdx.z;
  const int qg0 = blockIdx.x * QT + wave * 32;      // wave's first q row
  const size_t kvz = (size_t)z * KVRANGE;
  const int swzm = (l15 & 7) << 4;
  char* Pw = smem + 65536 + wave * 2048;

  // Q fragments (B-operand): lane holds Q[q=l15(+16qt)][h = 8*l4+i+32*kc]
  const unsigned short* qp0 = qws + ((size_t)b * N_ + qg0 + l15) * H_;
  short8 qf0[4], qf1[4];
#pragma unroll
  for (int kc = 0; kc < 4; ++kc) {
    qf0[kc] = *(const short8*)(qp0 + 8 * l4 + 32 * kc);
    qf1[kc] = *(const short8*)(qp0 + 16 * H_ + 8 * l4 + 32 * kc);
  }

  f32x4 O0[8], O1[8];
#pragma unroll
  for (int i = 0; i < 8; ++i) { O0[i] = (f32x4){0,0,0,0}; O1[i] = (f32x4){0,0,0,0}; }
  float m0 = -__builtin_inff(), l0 = 0.f, m1 = -__builtin_inff(), l1 = 0.f;

  const char* kbase = (const char*)(kws + ((size_t)b * N_ + kvz) * H_);
  const char* vbase = (const char*)(vtws + (size_t)b * H_ * N_) + kvz * 2;

  auto stage = [&](int buf, int step) {
    const char* kt = kbase + (size_t)step * KVB * H_ * 2;  // 16KB, row-major [64][128]
    char* kd = Kb0 + buf * 16384;
#pragma unroll
    for (int i = 0; i < 4; ++i) {
      int off = (tid + 256 * i) * 16;
      int row = off >> 8, col = off & 255;
      gl_lds16(kt + row * 256 + (col ^ ((row & 7) << 4)), kd + off);
    }
    const char* vt0 = vbase + (size_t)step * KVB * 2;      // [h][kv] rows stride N_*2
    char* vd = Vb0 + buf * 16384;
#pragma unroll
    for (int i = 0; i < 4; ++i) {
      int off = (tid + 256 * i) * 16;
      int h = off >> 7, colb = off & 127;
      gl_lds16(vt0 + (size_t)h * (N_ * 2) + (colb ^ ((h & 7) << 4)), vd + off);
    }
  };

  // online softmax on S^T (lane-local row) + P-tile prep for PV
  auto softmax_prep = [&](f32x4 (&S)[4], float& m, float& l, f32x4 (&O)[8], short8 (&pf)[2]) {
    float mx = S[0][0];
#pragma unroll
    for (int ct = 0; ct < 4; ++ct)
#pragma unroll
      for (int r = 0; r < 4; ++r) mx = fmaxf(mx, S[ct][r]);
    mx = fmaxf(mx, __shfl_xor(mx, 16));
    mx = fmaxf(mx, __shfl_xor(mx, 32));
    float mi = fmaxf(m, mx);
    float alpha = __builtin_amdgcn_exp2f(m - mi);
    m = mi;
    float rs = 0.f;
    uint2 pk[4];
#pragma unroll
    for (int ct = 0; ct < 4; ++ct) {
      float p0 = __builtin_amdgcn_exp2f(S[ct][0] - mi);
      float p1 = __builtin_amdgcn_exp2f(S[ct][1] - mi);
      float p2 = __builtin_amdgcn_exp2f(S[ct][2] - mi);
      float p3 = __builtin_amdgcn_exp2f(S[ct][3] - mi);
      rs += (p0 + p1) + (p2 + p3);
      pk[ct].x = (unsigned)f2bf(p0) | ((unsigned)f2bf(p1) << 16);
      pk[ct].y = (unsigned)f2bf(p2) | ((unsigned)f2bf(p3) << 16);
    }
    rs += __shfl_xor(rs, 16);
    rs += __shfl_xor(rs, 32);
    l = l * alpha + rs;
#pragma unroll
    for (int i = 0; i < 8; ++i) O[i] = O[i] * alpha;
    // P[q=l15][kv]: lane writes its 16 p-values as 4x b64 (kv = 16ct+4l4 .. +3)
#pragma unroll
    for (int ct = 0; ct < 4; ++ct)
      *(uint2*)(Pw + ((l15 * 128 + 32 * ct + 8 * l4) ^ swzm)) = pk[ct];
    // B-frag read: P[q=l15][kv = 8*l4+i+32*kc2]
    pf[0] = *(const short8*)(Pw + ((l15 * 128 + 16 * l4) ^ swzm));
    pf[1] = *(const short8*)(Pw + ((l15 * 128 + 16 * l4 + 64) ^ swzm));
  };

  stage(0, 0);
  __syncthreads();
  int cur = 0;

  for (int st = 0; st < NST; ++st) {
    if (st + 1 < NST) stage(cur ^ 1, st + 1);   // prefetch next tile

    const char* Kl = Kb0 + cur * 16384;
    const char* Vl = Vb0 + cur * 16384;

    // ---- QK^T (swapped): S^T[kv][q], A-frag = K row, reused for both q-tiles ----
    f32x4 S0[4], S1[4];
#pragma unroll
    for (int ct = 0; ct < 4; ++ct) { S0[ct] = (f32x4){0,0,0,0}; S1[ct] = (f32x4){0,0,0,0}; }
    __builtin_amdgcn_s_setprio(1);
#pragma unroll
    for (int ct = 0; ct < 4; ++ct) {
      int kr = 16 * ct + l15;
#pragma unroll
      for (int kc = 0; kc < 4; ++kc) {
        short8 af = *(const short8*)(Kl + ((kr * 256 + 16 * l4 + 64 * kc) ^ ((kr & 7) << 4)));
        S0[ct] = __builtin_amdgcn_mfma_f32_16x16x32_bf16(af, qf0[kc], S0[ct], 0, 0, 0);
        S1[ct] = __builtin_amdgcn_mfma_f32_16x16x32_bf16(af, qf1[kc], S1[ct], 0, 0, 0);
      }
    }
    __builtin_amdgcn_s_setprio(0);

    short8 pf0[2], pf1[2];
    softmax_prep(S0, m0, l0, O0, pf0);
    softmax_prep(S1, m1, l1, O1, pf1);

    // ---- PV (swapped): O^T[h][q] += V^T[h][kv] x P^T[kv][q]; V-frag reused x2 ----
    __builtin_amdgcn_s_setprio(1);
#pragma unroll
    for (int ct2 = 0; ct2 < 8; ++ct2) {
      int hr = 16 * ct2 + l15;
#pragma unroll
      for (int kc2 = 0; kc2 < 2; ++kc2) {
        short8 vf = *(const short8*)(Vl + ((hr * 128 + 16 * l4 + 64 * kc2) ^ ((hr & 7) << 4)));
        O0[ct2] = __builtin_amdgcn_mfma_f32_16x16x32_bf16(vf, pf0[kc2], O0[ct2], 0, 0, 0);
        O1[ct2] = __builtin_amdgcn_mfma_f32_16x16x32_bf16(vf, pf1[kc2], O1[ct2], 0, 0, 0);
      }
    }
    __builtin_amdgcn_s_setprio(0);

    __syncthreads();   // prefetch landed + all waves done with cur
    cur ^= 1;
  }

  // ---- epilogue: O^T -> LDS transpose -> coalesced partial store + m/l ----
  // (past last barrier; K/V buffers are free: use smem[0..64KB) as [128 q][512B])
#pragma unroll
  for (int ct2 = 0; ct2 < 8; ++ct2) {
    int q0 = wave * 32 + l15;
    *(f32x4*)(smem + q0 * 512 + ((64 * ct2 + 16 * l4) ^ ((q0 & 7) << 4))) = O0[ct2];
    int q1 = q0 + 16;
    *(f32x4*)(smem + q1 * 512 + ((64 * ct2 + 16 * l4) ^ ((q1 & 7) << 4))) = O1[ct2];
  }
  if (l4 == 0) {
    size_t r0 = ((size_t)z * B_ + b) * N_ + qg0 + l15;
    mlpart[2 * r0] = m0;
    mlpart[2 * r0 + 1] = l0;
    mlpart[2 * (r0 + 16)] = m1;
    mlpart[2 * (r0 + 16) + 1] = l1;
  }
  __syncthreads();
  float* od = opart + (((size_t)z * B_ + b) * N_ + (size_t)blockIdx.x * QT) * H_;
#pragma unroll
  for (int i = 0; i < 16; ++i) {
    int off = (tid + 256 * i) * 16;
    int q = off >> 9, colb = off & 511;
    f32x4 val = *(const f32x4*)(smem + q * 512 + (colb ^ ((q & 7) << 4)));
    *(f32x4*)((char*)od + (size_t)q * 512 + colb) = val;
  }
}

// ---------------- combine the two kv-split partials ----------------
__global__ void combine_k(const float* __restrict__ opart, const float* __restrict__ mlpart,
                          float* __restrict__ out) {
  const int t = threadIdx.x;
  size_t row = (size_t)blockIdx.x * 8 + (t >> 5);
  int hc = (t & 31) * 4;
  float mA = mlpart[2 * row], lA = mlpart[2 * row + 1];
  float mB = mlpart[2 * ((size_t)B_ * N_ + row)], lB = mlpart[2 * ((size_t)B_ * N_ + row) + 1];
  float mi = fmaxf(mA, mB);
  float aA = __builtin_amdgcn_exp2f(mA - mi);
  float aB = __builtin_amdgcn_exp2f(mB - mi);
  float rinv = 1.f / (aA * lA + aB * lB);
  f32x4 oA = *(const f32x4*)(opart + row * H_ + hc);
  f32x4 oB = *(const f32x4*)(opart + (size_t)B_ * N_ * H_ + row * H_ + hc);
  f32x4 res = (oA * (aA * rinv)) + (oB * (aB * rinv));
  *(f32x4*)(out + row * H_ + hc) = res;
}

// ================= R2 fallback path (ws >= 3*TSB only) =================
constexpr int FB_QTILE = 64;
constexpr int FB_KVSTEP = 128;
constexpr int FB_KVHALF = 64;
constexpr int FB_NTH = 512;
constexpr int FB_NSTEPS = N_ / FB_KVSTEP;

__global__ __launch_bounds__(FB_NTH, 2)
void fattn_fast(const unsigned short* __restrict__ qws,
                const unsigned short* __restrict__ kws,
                const unsigned short* __restrict__ vtws,
                float* __restrict__ out) {
  __shared__ unsigned short Kbuf[2][FB_KVSTEP * H_];
  __shared__ unsigned short Vbuf[2][H_ * FB_KVSTEP];
  __shared__ unsigned short Plds[8][16 * FB_KVHALF];
  __shared__ float MLlds[4][16][2];

  const int tid = threadIdx.x;
  const int wave = tid >> 6;
  const int lane = tid & 63;
  const int l15 = lane & 15;
  const int l4 = lane >> 4;
  const int sub = wave & 3;
  const int grp = wave >> 2;

  const int b = blockIdx.y;
  const int qbase = blockIdx.x * FB_QTILE;

  const unsigned short* qp = qws + ((size_t)b * N_ + qbase + sub * 16 + l15) * H_;
  short8 qfrag[4];
#pragma unroll
  for (int kc = 0; kc < 4; ++kc)
    qfrag[kc] = *(const short8*)(qp + 8 * l4 + 32 * kc);

  f32x4 Oacc[8];
#pragma unroll
  for (int i = 0; i < 8; ++i) Oacc[i] = (f32x4){0.f, 0.f, 0.f, 0.f};
  float mrun[4], lrun[4];
#pragma unroll
  for (int r = 0; r < 4; ++r) { mrun[r] = -__builtin_inff(); lrun[r] = 0.f; }

  const char* kbase = (const char*)(kws + (size_t)b * N_ * H_);
  const char* vbase = (const char*)(vtws + (size_t)b * H_ * N_);
  const int kvbase = grp * FB_KVHALF;
  char* pbase = (char*)Plds[wave];

  auto stage = [&](int buf, int step) {
    const char* ktile = kbase + (size_t)step * FB_KVSTEP * H_ * 2;
#pragma unroll
    for (int i = 0; i < 4; ++i) {
      int chunk = wave * 4 + i;
      int off = chunk * 1024 + lane * 16;
      int row = off >> 8, col = off & 255;
      gl_lds16(ktile + row * 256 + (col ^ ((row & 7) << 4)),
               (char*)Kbuf[buf] + chunk * 1024);
    }
#pragma unroll
    for (int i = 0; i < 4; ++i) {
      int chunk = wave * 4 + i;
      int h = chunk * 4 + (lane >> 4);
      int colb = (lane & 15) * 16;
      gl_lds16(vbase + (size_t)h * (N_ * 2) + (size_t)step * 256 + (colb ^ ((h & 7) << 4)),
               (char*)Vbuf[buf] + chunk * 1024);
    }
  };

  int cur = 0;
  stage(0, 0);
  __syncthreads();

  for (int step = 0; step < FB_NSTEPS; ++step) {
    if (step + 1 < FB_NSTEPS) stage(cur ^ 1, step + 1);

    const char* Kl = (const char*)Kbuf[cur];
    const char* Vl = (const char*)Vbuf[cur];

    f32x4 S[4];
#pragma unroll
    for (int ct = 0; ct < 4; ++ct) S[ct] = (f32x4){0.f, 0.f, 0.f, 0.f};
#pragma unroll
    for (int ct = 0; ct < 4; ++ct) {
      int kvrow = kvbase + ct * 16 + l15;
#pragma unroll
      for (int kc = 0; kc < 4; ++kc) {
        short8 bfrag = *(const short8*)(Kl +
            swz(kvrow * 256 + (8 * l4 + 32 * kc) * 2, kvrow));
        S[ct] = __builtin_amdgcn_mfma_f32_16x16x32_bf16(qfrag[kc], bfrag, S[ct], 0, 0, 0);
      }
    }

    float mnew[4];
#pragma unroll
    for (int r = 0; r < 4; ++r) {
      float mx = fmaxf(fmaxf(S[0][r], S[1][r]), fmaxf(S[2][r], S[3][r]));
      mx = fmaxf(mx, __shfl_xor(mx, 1));
      mx = fmaxf(mx, __shfl_xor(mx, 2));
      mx = fmaxf(mx, __shfl_xor(mx, 4));
      mx = fmaxf(mx, __shfl_xor(mx, 8));
      mnew[r] = mx;
    }
    float alpha[4];
#pragma unroll
    for (int r = 0; r < 4; ++r) {
      float mi = fmaxf(mrun[r], mnew[r]);
      alpha[r] = __builtin_amdgcn_exp2f(mrun[r] - mi);
      mrun[r] = mi;
    }
    float rsum[4] = {0.f, 0.f, 0.f, 0.f};
    unsigned short pb[4][4];
#pragma unroll
    for (int ct = 0; ct < 4; ++ct)
#pragma unroll
      for (int r = 0; r < 4; ++r) {
        float pv = __builtin_amdgcn_exp2f(S[ct][r] - mrun[r]);
        rsum[r] += pv;
        pb[ct][r] = f2bf(pv);
      }
#pragma unroll
    for (int r = 0; r < 4; ++r) {
      float s = rsum[r];
      s += __shfl_xor(s, 1); s += __shfl_xor(s, 2);
      s += __shfl_xor(s, 4); s += __shfl_xor(s, 8);
      lrun[r] = lrun[r] * alpha[r] + s;
    }
#pragma unroll
    for (int ct2 = 0; ct2 < 8; ++ct2)
#pragma unroll
      for (int r = 0; r < 4; ++r) Oacc[ct2][r] *= alpha[r];

#pragma unroll
    for (int ct = 0; ct < 4; ++ct)
#pragma unroll
      for (int r = 0; r < 4; ++r) {
        int qrow = 4 * l4 + r;
        int kv = l15 + 16 * ct;
        *(unsigned short*)(pbase + swz(qrow * 128 + kv * 2, qrow)) = pb[ct][r];
      }

#pragma unroll
    for (int kc2 = 0; kc2 < 2; ++kc2) {
      short8 afrag = *(const short8*)(pbase +
          swz(l15 * 128 + (8 * l4 + 32 * kc2) * 2, l15));
#pragma unroll
      for (int ct2 = 0; ct2 < 8; ++ct2) {
        int h = l15 + 16 * ct2;
        short8 bfrag = *(const short8*)(Vl +
            swz(h * 256 + (kvbase + 8 * l4 + 32 * kc2) * 2, h));
        Oacc[ct2] = __builtin_amdgcn_mfma_f32_16x16x32_bf16(afrag, bfrag, Oacc[ct2], 0, 0, 0);
      }
    }

    __syncthreads();
    cur ^= 1;
  }

  __syncthreads();
  float* mergeO = (float*)Kbuf;
  if (grp == 1) {
#pragma unroll
    for (int ct2 = 0; ct2 < 8; ++ct2)
#pragma unroll
      for (int r = 0; r < 4; ++r) {
        int qrow = 4 * l4 + r, h = l15 + 16 * ct2;
        mergeO[(sub * 16 + qrow) * H_ + h] = Oacc[ct2][r];
      }
    if (l15 == 0) {
#pragma unroll
      for (int r = 0; r < 4; ++r) {
        int qrow = 4 * l4 + r;
        MLlds[sub][qrow][0] = mrun[r];
        MLlds[sub][qrow][1] = lrun[r];
      }
    }
  }
  __syncthreads();
  if (grp == 0) {
    float aA[4], aB[4], rl[4];
#pragma unroll
    for (int r = 0; r < 4; ++r) {
      int qrow = 4 * l4 + r;
      float mB = MLlds[sub][qrow][0], lB = MLlds[sub][qrow][1];
      float mi = fmaxf(mrun[r], mB);
      aA[r] = __builtin_amdgcn_exp2f(mrun[r] - mi);
      aB[r] = __builtin_amdgcn_exp2f(mB - mi);
      rl[r] = 1.f / (lrun[r] * aA[r] + lB * aB[r]);
    }
    float* outp = out + ((size_t)b * N_ + qbase + sub * 16) * H_;
#pragma unroll
    for (int ct2 = 0; ct2 < 8; ++ct2)
#pragma unroll
      for (int r = 0; r < 4; ++r) {
        int qrow = 4 * l4 + r, h = l15 + 16 * ct2;
        float ob = mergeO[(sub * 16 + qrow) * H_ + h];
        outp[(size_t)qrow * H_ + h] = (Oacc[ct2][r] * aA[r] + ob * aB[r]) * rl[r];
      }
  }
}

extern "C" void kernel_launch(void* const* d_in, const int* in_sizes, int n_in,
                              void* d_out, int out_size, void* d_ws, size_t ws_size,
                              hipStream_t stream) {
  const float* q = (const float*)d_in[0];
  const float* k = (const float*)d_in[1];
  const float* v = (const float*)d_in[2];
  float* out = (float*)d_out;

  const size_t need_v3 = 3 * TSB + (size_t)KSPLIT * ELEMS * 4 + (size_t)KSPLIT * B_ * N_ * 2 * 4;
  if (ws_size >= need_v3) {
    unsigned short* qb = (unsigned short*)d_ws;
    unsigned short* kb = qb + ELEMS;
    unsigned short* vt = kb + ELEMS;
    float* opart = (float*)((char*)d_ws + 3 * TSB);
    float* mlpart = opart + (size_t)KSPLIT * ELEMS;
    conv_qk<<<dim3((unsigned)(ELEMS / 8 / 256)), dim3(256), 0, stream>>>(q, k, qb, kb);
    conv_vt<<<dim3(N_ / 64, H_ / 64, B_), dim3(256), 0, stream>>>(v, vt);
    fattn_v3<<<dim3(N_ / QT, B_, KSPLIT), dim3(NTH), 0, stream>>>(qb, kb, vt, opart, mlpart);
    combine_k<<<dim3(B_ * N_ / 8), dim3(256), 0, stream>>>(opart, mlpart, out);
  } else if (ws_size >= 3 * TSB) {
    unsigned short* qb = (unsigned short*)d_ws;
    unsigned short* kb = qb + ELEMS;
    unsigned short* vt = kb + ELEMS;
    conv_qk<<<dim3((unsigned)(ELEMS / 8 / 256)), dim3(256), 0, stream>>>(q, k, qb, kb);
    conv_vt<<<dim3(N_ / 64, H_ / 64, B_), dim3(256), 0, stream>>>(v, vt);
    fattn_fast<<<dim3(N_ / FB_QTILE, B_), dim3(FB_NTH), 0, stream>>>(qb, kb, vt, out);
  }
}

// Round 4
// 73.541 us; speedup vs baseline: 2.9344x; 1.1594x over previous
//
#include <hip/hip_runtime.h>

typedef __attribute__((ext_vector_type(4))) float f32x4;
typedef __attribute__((ext_vector_type(8))) short short8;

#define DEVI static __device__ __forceinline__

constexpr int B_ = 4;
constexpr int N_ = 4096;
constexpr int H_ = 128;
constexpr size_t ELEMS = (size_t)B_ * N_ * H_;   // per tensor
constexpr size_t TSB = ELEMS * 2;                // bf16 bytes per tensor

// ---- v4 geometry ----
constexpr int QT = 128;                 // q rows per block (4 waves x 32)
constexpr int KVB = 64;                 // kv rows per step
constexpr int NTH = 256;                // 4 waves

DEVI unsigned short f2bf(float x) {
  union { float f; unsigned u; } a; a.f = x;
  unsigned u = a.u;
  return (unsigned short)((u + 0x7FFFu + ((u >> 16) & 1u)) >> 16);  // RNE
}

DEVI int swz(int byteoff, int row) { return byteoff ^ ((row & 7) << 4); }

DEVI void gl_lds16(const void* g, void* l) {
  __builtin_amdgcn_global_load_lds(
      (const __attribute__((address_space(1))) void*)g,
      (__attribute__((address_space(3))) void*)l, 16, 0, 0);
}

// ---------------- pre-pass: convert Q(scaled)/K to bf16 ----------------
__global__ void conv_qk(const float* __restrict__ q, const float* __restrict__ k,
                        unsigned short* __restrict__ qb, unsigned short* __restrict__ kb) {
  const float qscale = 0.08838834764831845f * 1.4426950408889634f;  // 1/sqrt(H)*log2e
  size_t i = (size_t)blockIdx.x * blockDim.x + threadIdx.x;  // vec8 index
  {
    const float4* s = (const float4*)q + 2 * i;
    float4 a = s[0], b = s[1];
    short8 t;
    t[0] = (short)f2bf(a.x * qscale); t[1] = (short)f2bf(a.y * qscale);
    t[2] = (short)f2bf(a.z * qscale); t[3] = (short)f2bf(a.w * qscale);
    t[4] = (short)f2bf(b.x * qscale); t[5] = (short)f2bf(b.y * qscale);
    t[6] = (short)f2bf(b.z * qscale); t[7] = (short)f2bf(b.w * qscale);
    *(short8*)(qb + i * 8) = t;
  }
  {
    const float4* s = (const float4*)k + 2 * i;
    float4 a = s[0], b = s[1];
    short8 t;
    t[0] = (short)f2bf(a.x); t[1] = (short)f2bf(a.y);
    t[2] = (short)f2bf(a.z); t[3] = (short)f2bf(a.w);
    t[4] = (short)f2bf(b.x); t[5] = (short)f2bf(b.y);
    t[6] = (short)f2bf(b.z); t[7] = (short)f2bf(b.w);
    *(short8*)(kb + i * 8) = t;
  }
}

// ---------------- pre-pass: V -> V^T bf16 ([b][h][n]) ----------------
__global__ void conv_vt(const float* __restrict__ v, unsigned short* __restrict__ vt) {
  __shared__ unsigned short T[64][72];
  const int n0 = blockIdx.x * 64, h0 = blockIdx.y * 64, b = blockIdx.z;
  const int t = threadIdx.x;
  const int c4 = t & 15, r = t >> 4;
#pragma unroll
  for (int i = 0; i < 4; ++i) {
    int n = n0 + r + 16 * i;
    float4 val = *(const float4*)(v + ((size_t)b * N_ + n) * H_ + h0 + 4 * c4);
    T[4 * c4 + 0][r + 16 * i] = f2bf(val.x);
    T[4 * c4 + 1][r + 16 * i] = f2bf(val.y);
    T[4 * c4 + 2][r + 16 * i] = f2bf(val.z);
    T[4 * c4 + 3][r + 16 * i] = f2bf(val.w);
  }
  __syncthreads();
  const int c8 = t & 7, hr = t >> 3;
#pragma unroll
  for (int i = 0; i < 2; ++i) {
    int hl = hr + 32 * i;
    short8 val = *(const short8*)(&T[hl][8 * c8]);
    *(short8*)(vt + ((size_t)b * H_ + h0 + hl) * N_ + n0 + 8 * c8) = val;
  }
}

// ---------------- main: swapped-operand flash attention, KS-way kv split ----------------
template <int KS>
__global__ __launch_bounds__(NTH, 2)
void fattn_v4(const unsigned short* __restrict__ qws,
              const unsigned short* __restrict__ kws,
              const unsigned short* __restrict__ vtws,
              float* __restrict__ opart, float* __restrict__ mlpart) {
  constexpr int KVRANGE = N_ / KS;
  constexpr int NST = KVRANGE / KVB;

  __shared__ __align__(16) char smem[73728];
  char* Kb0 = smem;             // 16KB x2 (double buffer)
  char* Vb0 = smem + 32768;     // 16KB x2

  const int tid = threadIdx.x, wave = tid >> 6, lane = tid & 63;
  const int l15 = lane & 15, l4 = lane >> 4;
  const int b = blockIdx.y, z = blockIdx.z;
  const int qg0 = blockIdx.x * QT + wave * 32;
  const size_t kvz = (size_t)z * KVRANGE;
  const int swzm = (l15 & 7) << 4;
  char* Pw = smem + 65536 + wave * 2048;

  const unsigned short* qp0 = qws + ((size_t)b * N_ + qg0 + l15) * H_;
  short8 qf0[4], qf1[4];
#pragma unroll
  for (int kc = 0; kc < 4; ++kc) {
    qf0[kc] = *(const short8*)(qp0 + 8 * l4 + 32 * kc);
    qf1[kc] = *(const short8*)(qp0 + 16 * H_ + 8 * l4 + 32 * kc);
  }

  f32x4 O0[8], O1[8];
#pragma unroll
  for (int i = 0; i < 8; ++i) { O0[i] = (f32x4){0,0,0,0}; O1[i] = (f32x4){0,0,0,0}; }
  float m0 = -__builtin_inff(), l0 = 0.f, m1 = -__builtin_inff(), l1 = 0.f;

  const char* kbase = (const char*)(kws + ((size_t)b * N_ + kvz) * H_);
  const char* vbase = (const char*)(vtws + (size_t)b * H_ * N_) + kvz * 2;

  auto stage = [&](int buf, int step) {
    const char* kt = kbase + (size_t)step * KVB * H_ * 2;  // 16KB [64][128]
    char* kd = Kb0 + buf * 16384;
#pragma unroll
    for (int i = 0; i < 4; ++i) {
      int off = (tid + 256 * i) * 16;
      int row = off >> 8, col = off & 255;
      gl_lds16(kt + row * 256 + (col ^ ((row & 7) << 4)), kd + off);
    }
    const char* vt0 = vbase + (size_t)step * KVB * 2;      // [h][kv], row stride N_*2
    char* vd = Vb0 + buf * 16384;
#pragma unroll
    for (int i = 0; i < 4; ++i) {
      int off = (tid + 256 * i) * 16;
      int h = off >> 7, colb = off & 127;
      gl_lds16(vt0 + (size_t)h * (N_ * 2) + (colb ^ ((h & 7) << 4)), vd + off);
    }
  };

  auto softmax_prep = [&](f32x4 (&S)[4], float& m, float& l, f32x4 (&O)[8], short8 (&pf)[2]) {
    float mx = S[0][0];
#pragma unroll
    for (int ct = 0; ct < 4; ++ct)
#pragma unroll
      for (int r = 0; r < 4; ++r) mx = fmaxf(mx, S[ct][r]);
    mx = fmaxf(mx, __shfl_xor(mx, 16));
    mx = fmaxf(mx, __shfl_xor(mx, 32));
    float mi = fmaxf(m, mx);
    float alpha = __builtin_amdgcn_exp2f(m - mi);
    m = mi;
    float rs = 0.f;
    uint2 pk[4];
#pragma unroll
    for (int ct = 0; ct < 4; ++ct) {
      float p0 = __builtin_amdgcn_exp2f(S[ct][0] - mi);
      float p1 = __builtin_amdgcn_exp2f(S[ct][1] - mi);
      float p2 = __builtin_amdgcn_exp2f(S[ct][2] - mi);
      float p3 = __builtin_amdgcn_exp2f(S[ct][3] - mi);
      rs += (p0 + p1) + (p2 + p3);
      pk[ct].x = (unsigned)f2bf(p0) | ((unsigned)f2bf(p1) << 16);
      pk[ct].y = (unsigned)f2bf(p2) | ((unsigned)f2bf(p3) << 16);
    }
    rs += __shfl_xor(rs, 16);
    rs += __shfl_xor(rs, 32);
    l = l * alpha + rs;
#pragma unroll
    for (int i = 0; i < 8; ++i) O[i] = O[i] * alpha;
#pragma unroll
    for (int ct = 0; ct < 4; ++ct)
      *(uint2*)(Pw + ((l15 * 128 + 32 * ct + 8 * l4) ^ swzm)) = pk[ct];
    pf[0] = *(const short8*)(Pw + ((l15 * 128 + 16 * l4) ^ swzm));
    pf[1] = *(const short8*)(Pw + ((l15 * 128 + 16 * l4 + 64) ^ swzm));
  };

  stage(0, 0);
  __syncthreads();
  int cur = 0;

  for (int st = 0; st < NST; ++st) {
    if (st + 1 < NST) stage(cur ^ 1, st + 1);

    const char* Kl = Kb0 + cur * 16384;
    const char* Vl = Vb0 + cur * 16384;

    f32x4 S0[4], S1[4];
#pragma unroll
    for (int ct = 0; ct < 4; ++ct) { S0[ct] = (f32x4){0,0,0,0}; S1[ct] = (f32x4){0,0,0,0}; }
    __builtin_amdgcn_s_setprio(1);
#pragma unroll
    for (int ct = 0; ct < 4; ++ct) {
      int kr = 16 * ct + l15;
#pragma unroll
      for (int kc = 0; kc < 4; ++kc) {
        short8 af = *(const short8*)(Kl + ((kr * 256 + 16 * l4 + 64 * kc) ^ ((kr & 7) << 4)));
        S0[ct] = __builtin_amdgcn_mfma_f32_16x16x32_bf16(af, qf0[kc], S0[ct], 0, 0, 0);
        S1[ct] = __builtin_amdgcn_mfma_f32_16x16x32_bf16(af, qf1[kc], S1[ct], 0, 0, 0);
      }
    }
    __builtin_amdgcn_s_setprio(0);

    short8 pf0[2], pf1[2];
    softmax_prep(S0, m0, l0, O0, pf0);
    softmax_prep(S1, m1, l1, O1, pf1);

    __builtin_amdgcn_s_setprio(1);
#pragma unroll
    for (int ct2 = 0; ct2 < 8; ++ct2) {
      int hr = 16 * ct2 + l15;
#pragma unroll
      for (int kc2 = 0; kc2 < 2; ++kc2) {
        short8 vf = *(const short8*)(Vl + ((hr * 128 + 16 * l4 + 64 * kc2) ^ ((hr & 7) << 4)));
        O0[ct2] = __builtin_amdgcn_mfma_f32_16x16x32_bf16(vf, pf0[kc2], O0[ct2], 0, 0, 0);
        O1[ct2] = __builtin_amdgcn_mfma_f32_16x16x32_bf16(vf, pf1[kc2], O1[ct2], 0, 0, 0);
      }
    }
    __builtin_amdgcn_s_setprio(0);

    __syncthreads();
    cur ^= 1;
  }

  // ---- epilogue: O^T -> LDS transpose -> coalesced partial store + m/l ----
#pragma unroll
  for (int ct2 = 0; ct2 < 8; ++ct2) {
    int q0 = wave * 32 + l15;
    *(f32x4*)(smem + q0 * 512 + ((64 * ct2 + 16 * l4) ^ ((q0 & 7) << 4))) = O0[ct2];
    int q1 = q0 + 16;
    *(f32x4*)(smem + q1 * 512 + ((64 * ct2 + 16 * l4) ^ ((q1 & 7) << 4))) = O1[ct2];
  }
  if (l4 == 0) {
    size_t r0 = ((size_t)z * B_ + b) * N_ + qg0 + l15;
    mlpart[2 * r0] = m0;
    mlpart[2 * r0 + 1] = l0;
    mlpart[2 * (r0 + 16)] = m1;
    mlpart[2 * (r0 + 16) + 1] = l1;
  }
  __syncthreads();
  float* od = opart + (((size_t)z * B_ + b) * N_ + (size_t)blockIdx.x * QT) * H_;
#pragma unroll
  for (int i = 0; i < 16; ++i) {
    int off = (tid + 256 * i) * 16;
    int q = off >> 9, colb = off & 511;
    f32x4 val = *(const f32x4*)(smem + q * 512 + (colb ^ ((q & 7) << 4)));
    *(f32x4*)((char*)od + (size_t)q * 512 + colb) = val;
  }
}

// ---------------- combine the KS kv-split partials ----------------
template <int KS>
__global__ void combine_k(const float* __restrict__ opart, const float* __restrict__ mlpart,
                          float* __restrict__ out) {
  const int t = threadIdx.x;
  size_t row = (size_t)blockIdx.x * 8 + (t >> 5);
  int hc = (t & 31) * 4;
  float mz[KS], lz[KS];
  float mi = -__builtin_inff();
#pragma unroll
  for (int z = 0; z < KS; ++z) {
    size_t r = (size_t)z * B_ * N_ + row;
    mz[z] = mlpart[2 * r];
    lz[z] = mlpart[2 * r + 1];
    mi = fmaxf(mi, mz[z]);
  }
  float lsum = 0.f;
  float az[KS];
#pragma unroll
  for (int z = 0; z < KS; ++z) {
    az[z] = __builtin_amdgcn_exp2f(mz[z] - mi);
    lsum += az[z] * lz[z];
  }
  float rinv = 1.f / lsum;
  f32x4 acc = (f32x4){0, 0, 0, 0};
#pragma unroll
  for (int z = 0; z < KS; ++z) {
    f32x4 oz = *(const f32x4*)(opart + (size_t)z * B_ * N_ * H_ + row * H_ + hc);
    acc = acc + oz * (az[z] * rinv);
  }
  *(f32x4*)(out + row * H_ + hc) = acc;
}

// ================= R2 fallback path (minimal ws) =================
constexpr int FB_QTILE = 64;
constexpr int FB_KVSTEP = 128;
constexpr int FB_KVHALF = 64;
constexpr int FB_NTH = 512;
constexpr int FB_NSTEPS = N_ / FB_KVSTEP;

__global__ __launch_bounds__(FB_NTH, 2)
void fattn_fast(const unsigned short* __restrict__ qws,
                const unsigned short* __restrict__ kws,
                const unsigned short* __restrict__ vtws,
                float* __restrict__ out) {
  __shared__ unsigned short Kbuf[2][FB_KVSTEP * H_];
  __shared__ unsigned short Vbuf[2][H_ * FB_KVSTEP];
  __shared__ unsigned short Plds[8][16 * FB_KVHALF];
  __shared__ float MLlds[4][16][2];

  const int tid = threadIdx.x;
  const int wave = tid >> 6;
  const int lane = tid & 63;
  const int l15 = lane & 15;
  const int l4 = lane >> 4;
  const int sub = wave & 3;
  const int grp = wave >> 2;

  const int b = blockIdx.y;
  const int qbase = blockIdx.x * FB_QTILE;

  const unsigned short* qp = qws + ((size_t)b * N_ + qbase + sub * 16 + l15) * H_;
  short8 qfrag[4];
#pragma unroll
  for (int kc = 0; kc < 4; ++kc)
    qfrag[kc] = *(const short8*)(qp + 8 * l4 + 32 * kc);

  f32x4 Oacc[8];
#pragma unroll
  for (int i = 0; i < 8; ++i) Oacc[i] = (f32x4){0.f, 0.f, 0.f, 0.f};
  float mrun[4], lrun[4];
#pragma unroll
  for (int r = 0; r < 4; ++r) { mrun[r] = -__builtin_inff(); lrun[r] = 0.f; }

  const char* kbase = (const char*)(kws + (size_t)b * N_ * H_);
  const char* vbase = (const char*)(vtws + (size_t)b * H_ * N_);
  const int kvbase = grp * FB_KVHALF;
  char* pbase = (char*)Plds[wave];

  auto stage = [&](int buf, int step) {
    const char* ktile = kbase + (size_t)step * FB_KVSTEP * H_ * 2;
#pragma unroll
    for (int i = 0; i < 4; ++i) {
      int chunk = wave * 4 + i;
      int off = chunk * 1024 + lane * 16;
      int row = off >> 8, col = off & 255;
      gl_lds16(ktile + row * 256 + (col ^ ((row & 7) << 4)),
               (char*)Kbuf[buf] + chunk * 1024);
    }
#pragma unroll
    for (int i = 0; i < 4; ++i) {
      int chunk = wave * 4 + i;
      int h = chunk * 4 + (lane >> 4);
      int colb = (lane & 15) * 16;
      gl_lds16(vbase + (size_t)h * (N_ * 2) + (size_t)step * 256 + (colb ^ ((h & 7) << 4)),
               (char*)Vbuf[buf] + chunk * 1024);
    }
  };

  int cur = 0;
  stage(0, 0);
  __syncthreads();

  for (int step = 0; step < FB_NSTEPS; ++step) {
    if (step + 1 < FB_NSTEPS) stage(cur ^ 1, step + 1);

    const char* Kl = (const char*)Kbuf[cur];
    const char* Vl = (const char*)Vbuf[cur];

    f32x4 S[4];
#pragma unroll
    for (int ct = 0; ct < 4; ++ct) S[ct] = (f32x4){0.f, 0.f, 0.f, 0.f};
#pragma unroll
    for (int ct = 0; ct < 4; ++ct) {
      int kvrow = kvbase + ct * 16 + l15;
#pragma unroll
      for (int kc = 0; kc < 4; ++kc) {
        short8 bfrag = *(const short8*)(Kl +
            swz(kvrow * 256 + (8 * l4 + 32 * kc) * 2, kvrow));
        S[ct] = __builtin_amdgcn_mfma_f32_16x16x32_bf16(qfrag[kc], bfrag, S[ct], 0, 0, 0);
      }
    }

    float mnew[4];
#pragma unroll
    for (int r = 0; r < 4; ++r) {
      float mx = fmaxf(fmaxf(S[0][r], S[1][r]), fmaxf(S[2][r], S[3][r]));
      mx = fmaxf(mx, __shfl_xor(mx, 1));
      mx = fmaxf(mx, __shfl_xor(mx, 2));
      mx = fmaxf(mx, __shfl_xor(mx, 4));
      mx = fmaxf(mx, __shfl_xor(mx, 8));
      mnew[r] = mx;
    }
    float alpha[4];
#pragma unroll
    for (int r = 0; r < 4; ++r) {
      float mi = fmaxf(mrun[r], mnew[r]);
      alpha[r] = __builtin_amdgcn_exp2f(mrun[r] - mi);
      mrun[r] = mi;
    }
    float rsum[4] = {0.f, 0.f, 0.f, 0.f};
    unsigned short pb[4][4];
#pragma unroll
    for (int ct = 0; ct < 4; ++ct)
#pragma unroll
      for (int r = 0; r < 4; ++r) {
        float pv = __builtin_amdgcn_exp2f(S[ct][r] - mrun[r]);
        rsum[r] += pv;
        pb[ct][r] = f2bf(pv);
      }
#pragma unroll
    for (int r = 0; r < 4; ++r) {
      float s = rsum[r];
      s += __shfl_xor(s, 1); s += __shfl_xor(s, 2);
      s += __shfl_xor(s, 4); s += __shfl_xor(s, 8);
      lrun[r] = lrun[r] * alpha[r] + s;
    }
#pragma unroll
    for (int ct2 = 0; ct2 < 8; ++ct2)
#pragma unroll
      for (int r = 0; r < 4; ++r) Oacc[ct2][r] *= alpha[r];

#pragma unroll
    for (int ct = 0; ct < 4; ++ct)
#pragma unroll
      for (int r = 0; r < 4; ++r) {
        int qrow = 4 * l4 + r;
        int kv = l15 + 16 * ct;
        *(unsigned short*)(pbase + swz(qrow * 128 + kv * 2, qrow)) = pb[ct][r];
      }

#pragma unroll
    for (int kc2 = 0; kc2 < 2; ++kc2) {
      short8 afrag = *(const short8*)(pbase +
          swz(l15 * 128 + (8 * l4 + 32 * kc2) * 2, l15));
#pragma unroll
      for (int ct2 = 0; ct2 < 8; ++ct2) {
        int h = l15 + 16 * ct2;
        short8 bfrag = *(const short8*)(Vl +
            swz(h * 256 + (kvbase + 8 * l4 + 32 * kc2) * 2, h));
        Oacc[ct2] = __builtin_amdgcn_mfma_f32_16x16x32_bf16(afrag, bfrag, Oacc[ct2], 0, 0, 0);
      }
    }

    __syncthreads();
    cur ^= 1;
  }

  __syncthreads();
  float* mergeO = (float*)Kbuf;
  if (grp == 1) {
#pragma unroll
    for (int ct2 = 0; ct2 < 8; ++ct2)
#pragma unroll
      for (int r = 0; r < 4; ++r) {
        int qrow = 4 * l4 + r, h = l15 + 16 * ct2;
        mergeO[(sub * 16 + qrow) * H_ + h] = Oacc[ct2][r];
      }
    if (l15 == 0) {
#pragma unroll
      for (int r = 0; r < 4; ++r) {
        int qrow = 4 * l4 + r;
        MLlds[sub][qrow][0] = mrun[r];
        MLlds[sub][qrow][1] = lrun[r];
      }
    }
  }
  __syncthreads();
  if (grp == 0) {
    float aA[4], aB[4], rl[4];
#pragma unroll
    for (int r = 0; r < 4; ++r) {
      int qrow = 4 * l4 + r;
      float mB = MLlds[sub][qrow][0], lB = MLlds[sub][qrow][1];
      float mi = fmaxf(mrun[r], mB);
      aA[r] = __builtin_amdgcn_exp2f(mrun[r] - mi);
      aB[r] = __builtin_amdgcn_exp2f(mB - mi);
      rl[r] = 1.f / (lrun[r] * aA[r] + lB * aB[r]);
    }
    float* outp = out + ((size_t)b * N_ + qbase + sub * 16) * H_;
#pragma unroll
    for (int ct2 = 0; ct2 < 8; ++ct2)
#pragma unroll
      for (int r = 0; r < 4; ++r) {
        int qrow = 4 * l4 + r, h = l15 + 16 * ct2;
        float ob = mergeO[(sub * 16 + qrow) * H_ + h];
        outp[(size_t)qrow * H_ + h] = (Oacc[ct2][r] * aA[r] + ob * aB[r]) * rl[r];
      }
  }
}

extern "C" void kernel_launch(void* const* d_in, const int* in_sizes, int n_in,
                              void* d_out, int out_size, void* d_ws, size_t ws_size,
                              hipStream_t stream) {
  const float* q = (const float*)d_in[0];
  const float* k = (const float*)d_in[1];
  const float* v = (const float*)d_in[2];
  float* out = (float*)d_out;

  auto need = [](int ks) {
    return 3 * TSB + (size_t)ks * ELEMS * 4 + (size_t)ks * B_ * N_ * 2 * 4;
  };

  if (ws_size >= need(4)) {
    unsigned short* qb = (unsigned short*)d_ws;
    unsigned short* kb = qb + ELEMS;
    unsigned short* vt = kb + ELEMS;
    float* opart = (float*)((char*)d_ws + 3 * TSB);
    float* mlpart = opart + (size_t)4 * ELEMS;
    conv_qk<<<dim3((unsigned)(ELEMS / 8 / 256)), dim3(256), 0, stream>>>(q, k, qb, kb);
    conv_vt<<<dim3(N_ / 64, H_ / 64, B_), dim3(256), 0, stream>>>(v, vt);
    fattn_v4<4><<<dim3(N_ / QT, B_, 4), dim3(NTH), 0, stream>>>(qb, kb, vt, opart, mlpart);
    combine_k<4><<<dim3(B_ * N_ / 8), dim3(256), 0, stream>>>(opart, mlpart, out);
  } else if (ws_size >= need(2)) {
    unsigned short* qb = (unsigned short*)d_ws;
    unsigned short* kb = qb + ELEMS;
    unsigned short* vt = kb + ELEMS;
    float* opart = (float*)((char*)d_ws + 3 * TSB);
    float* mlpart = opart + (size_t)2 * ELEMS;
    conv_qk<<<dim3((unsigned)(ELEMS / 8 / 256)), dim3(256), 0, stream>>>(q, k, qb, kb);
    conv_vt<<<dim3(N_ / 64, H_ / 64, B_), dim3(256), 0, stream>>>(v, vt);
    fattn_v4<2><<<dim3(N_ / QT, B_, 2), dim3(NTH), 0, stream>>>(qb, kb, vt, opart, mlpart);
    combine_k<2><<<dim3(B_ * N_ / 8), dim3(256), 0, stream>>>(opart, mlpart, out);
  } else if (ws_size >= 3 * TSB) {
    unsigned short* qb = (unsigned short*)d_ws;
    unsigned short* kb = qb + ELEMS;
    unsigned short* vt = kb + ELEMS;
    conv_qk<<<dim3((unsigned)(ELEMS / 8 / 256)), dim3(256), 0, stream>>>(q, k, qb, kb);
    conv_vt<<<dim3(N_ / 64, H_ / 64, B_), dim3(256), 0, stream>>>(v, vt);
    fattn_fast<<<dim3(N_ / FB_QTILE, B_), dim3(FB_NTH), 0, stream>>>(qb, kb, vt, out);
  }
}

// Round 5
// 72.001 us; speedup vs baseline: 2.9972x; 1.0214x over previous
//
#include <hip/hip_runtime.h>

typedef __attribute__((ext_vector_type(4))) float f32x4;
typedef __attribute__((ext_vector_type(8))) short short8;

#define DEVI static __device__ __forceinline__

constexpr int B_ = 4;
constexpr int N_ = 4096;
constexpr int H_ = 128;
constexpr size_t ELEMS = (size_t)B_ * N_ * H_;   // per tensor
constexpr size_t TSB = ELEMS * 2;                // bf16 bytes per tensor

// ---- v5 geometry ----
constexpr int QT = 128;                 // q rows per block (4 waves x 32)
constexpr int KVB = 64;                 // kv rows per step
constexpr int NTH = 256;                // 4 waves

DEVI unsigned short f2bf(float x) {
  union { float f; unsigned u; } a; a.f = x;
  unsigned u = a.u;
  return (unsigned short)((u + 0x7FFFu + ((u >> 16) & 1u)) >> 16);  // RNE
}

DEVI int swz(int byteoff, int row) { return byteoff ^ ((row & 7) << 4); }

DEVI void gl_lds16(const void* g, void* l) {
  __builtin_amdgcn_global_load_lds(
      (const __attribute__((address_space(1))) void*)g,
      (__attribute__((address_space(3))) void*)l, 16, 0, 0);
}

// ---------------- pre-pass: convert Q(scaled)/K to bf16 ----------------
__global__ void conv_qk(const float* __restrict__ q, const float* __restrict__ k,
                        unsigned short* __restrict__ qb, unsigned short* __restrict__ kb) {
  const float qscale = 0.08838834764831845f * 1.4426950408889634f;  // 1/sqrt(H)*log2e
  size_t i = (size_t)blockIdx.x * blockDim.x + threadIdx.x;  // vec8 index
  {
    const float4* s = (const float4*)q + 2 * i;
    float4 a = s[0], b = s[1];
    short8 t;
    t[0] = (short)f2bf(a.x * qscale); t[1] = (short)f2bf(a.y * qscale);
    t[2] = (short)f2bf(a.z * qscale); t[3] = (short)f2bf(a.w * qscale);
    t[4] = (short)f2bf(b.x * qscale); t[5] = (short)f2bf(b.y * qscale);
    t[6] = (short)f2bf(b.z * qscale); t[7] = (short)f2bf(b.w * qscale);
    *(short8*)(qb + i * 8) = t;
  }
  {
    const float4* s = (const float4*)k + 2 * i;
    float4 a = s[0], b = s[1];
    short8 t;
    t[0] = (short)f2bf(a.x); t[1] = (short)f2bf(a.y);
    t[2] = (short)f2bf(a.z); t[3] = (short)f2bf(a.w);
    t[4] = (short)f2bf(b.x); t[5] = (short)f2bf(b.y);
    t[6] = (short)f2bf(b.z); t[7] = (short)f2bf(b.w);
    *(short8*)(kb + i * 8) = t;
  }
}

// ---------------- pre-pass: V -> V^T bf16 ([b][h][n]) ----------------
__global__ void conv_vt(const float* __restrict__ v, unsigned short* __restrict__ vt) {
  __shared__ unsigned short T[64][72];
  const int n0 = blockIdx.x * 64, h0 = blockIdx.y * 64, b = blockIdx.z;
  const int t = threadIdx.x;
  const int c4 = t & 15, r = t >> 4;
#pragma unroll
  for (int i = 0; i < 4; ++i) {
    int n = n0 + r + 16 * i;
    float4 val = *(const float4*)(v + ((size_t)b * N_ + n) * H_ + h0 + 4 * c4);
    T[4 * c4 + 0][r + 16 * i] = f2bf(val.x);
    T[4 * c4 + 1][r + 16 * i] = f2bf(val.y);
    T[4 * c4 + 2][r + 16 * i] = f2bf(val.z);
    T[4 * c4 + 3][r + 16 * i] = f2bf(val.w);
  }
  __syncthreads();
  const int c8 = t & 7, hr = t >> 3;
#pragma unroll
  for (int i = 0; i < 2; ++i) {
    int hl = hr + 32 * i;
    short8 val = *(const short8*)(&T[hl][8 * c8]);
    *(short8*)(vt + ((size_t)b * H_ + h0 + hl) * N_ + n0 + 8 * c8) = val;
  }
}

// ---------------- main v5: XCD-local, defer-max flash attention ----------------
// 1-D grid; decode keeps each (b,z) K/V slice on ONE XCD so it stays L2-resident.
template <int KS>
__global__ __launch_bounds__(NTH, 2)
void fattn_v5(const unsigned short* __restrict__ qws,
              const unsigned short* __restrict__ kws,
              const unsigned short* __restrict__ vtws,
              float* __restrict__ opart, float* __restrict__ mlpart) {
  constexpr int KVRANGE = N_ / KS;
  constexpr int NST = KVRANGE / KVB;

  __shared__ __align__(16) char smem[73728];
  char* Kb0 = smem;             // 16KB x2 (double buffer)
  char* Vb0 = smem + 32768;     // 16KB x2

  const int tid = threadIdx.x, wave = tid >> 6, lane = tid & 63;
  const int l15 = lane & 15, l4 = lane >> 4;

  // XCD-locality decode: xcd = bid % 8 (HW round-robin). Each XCD owns
  // (16/KS... i.e. 2 for KS=4, 1 for KS=2) (b,z) pairs; K/V slice ~1MB -> L2-resident.
  const int bid = blockIdx.x;
  int x, b, z;
  if (KS == 4) {               // 512 blocks = 8 xcd * 2 pairs * 32 x
    int pair = (bid & 7) * 2 + ((bid >> 3) & 1);
    x = bid >> 4;
    b = pair >> 2;
    z = pair & 3;
  } else {                     // KS==2: 256 blocks = 8 pairs * 32 x
    int pair = bid & 7;
    x = bid >> 3;
    b = pair >> 1;
    z = pair & 1;
  }

  const int qg0 = x * QT + wave * 32;
  const size_t kvz = (size_t)z * KVRANGE;
  const int swzm = (l15 & 7) << 4;
  char* Pw = smem + 65536 + wave * 2048;

  const unsigned short* qp0 = qws + ((size_t)b * N_ + qg0 + l15) * H_;
  short8 qf0[4], qf1[4];
#pragma unroll
  for (int kc = 0; kc < 4; ++kc) {
    qf0[kc] = *(const short8*)(qp0 + 8 * l4 + 32 * kc);
    qf1[kc] = *(const short8*)(qp0 + 16 * H_ + 8 * l4 + 32 * kc);
  }

  f32x4 O0[8], O1[8];
#pragma unroll
  for (int i = 0; i < 8; ++i) { O0[i] = (f32x4){0,0,0,0}; O1[i] = (f32x4){0,0,0,0}; }
  // exp2-domain running max starts at 0 (valid: P bounded by 256 via defer test)
  float m0 = 0.f, l0 = 0.f, m1 = 0.f, l1 = 0.f;

  const char* kbase = (const char*)(kws + ((size_t)b * N_ + kvz) * H_);
  const char* vbase = (const char*)(vtws + (size_t)b * H_ * N_) + kvz * 2;

  auto stage = [&](int buf, int step) {
    const char* kt = kbase + (size_t)step * KVB * H_ * 2;  // 16KB [64][128]
    char* kd = Kb0 + buf * 16384;
#pragma unroll
    for (int i = 0; i < 4; ++i) {
      int off = (tid + 256 * i) * 16;
      int row = off >> 8, col = off & 255;
      gl_lds16(kt + row * 256 + (col ^ ((row & 7) << 4)), kd + off);
    }
    const char* vt0 = vbase + (size_t)step * KVB * 2;      // [h][kv], row stride N_*2
    char* vd = Vb0 + buf * 16384;
#pragma unroll
    for (int i = 0; i < 4; ++i) {
      int off = (tid + 256 * i) * 16;
      int h = off >> 7, colb = off & 127;
      gl_lds16(vt0 + (size_t)h * (N_ * 2) + (colb ^ ((h & 7) << 4)), vd + off);
    }
  };

  // defer-max online softmax: speculative p=exp2(S-m); rescale only if maxp>256
  auto softmax_prep = [&](f32x4 (&S)[4], float& m, float& l, f32x4 (&O)[8], short8 (&pf)[2]) {
    float p[16];
#pragma unroll
    for (int ct = 0; ct < 4; ++ct)
#pragma unroll
      for (int r = 0; r < 4; ++r)
        p[4 * ct + r] = __builtin_amdgcn_exp2f(S[ct][r] - m);
    // parallel trees for max (defer test) and sum
    float a0 = fmaxf(p[0], p[1]), a1 = fmaxf(p[2], p[3]);
    float a2 = fmaxf(p[4], p[5]), a3 = fmaxf(p[6], p[7]);
    float a4 = fmaxf(p[8], p[9]), a5 = fmaxf(p[10], p[11]);
    float a6 = fmaxf(p[12], p[13]), a7 = fmaxf(p[14], p[15]);
    float b0 = fmaxf(a0, a1), b1 = fmaxf(a2, a3), b2 = fmaxf(a4, a5), b3 = fmaxf(a6, a7);
    float mx = fmaxf(fmaxf(b0, b1), fmaxf(b2, b3));
    mx = fmaxf(mx, __shfl_xor(mx, 16));
    mx = fmaxf(mx, __shfl_xor(mx, 32));
    float s0 = (p[0] + p[1]) + (p[2] + p[3]);
    float s1 = (p[4] + p[5]) + (p[6] + p[7]);
    float s2 = (p[8] + p[9]) + (p[10] + p[11]);
    float s3 = (p[12] + p[13]) + (p[14] + p[15]);
    float rs = (s0 + s1) + (s2 + s3);
    rs += __shfl_xor(rs, 16);
    rs += __shfl_xor(rs, 32);
    if (__builtin_expect(!__all(mx <= 256.f), 0)) {
      // rare: renormalize this row so max p becomes 1
      float sc = fmaxf(mx, 1.f);
      float ai = 1.f / sc;
      m += __builtin_amdgcn_logf(sc);     // v_log_f32 = log2
      l = (l + rs) * ai;
#pragma unroll
      for (int i = 0; i < 16; ++i) p[i] *= ai;
#pragma unroll
      for (int i = 0; i < 8; ++i) O[i] = O[i] * ai;
    } else {
      l += rs;
    }
    // pack P (bf16) -> per-wave LDS tile -> read PV B-fragments
#pragma unroll
    for (int ct = 0; ct < 4; ++ct) {
      uint2 pk;
      pk.x = (unsigned)f2bf(p[4 * ct]) | ((unsigned)f2bf(p[4 * ct + 1]) << 16);
      pk.y = (unsigned)f2bf(p[4 * ct + 2]) | ((unsigned)f2bf(p[4 * ct + 3]) << 16);
      *(uint2*)(Pw + ((l15 * 128 + 32 * ct + 8 * l4) ^ swzm)) = pk;
    }
    pf[0] = *(const short8*)(Pw + ((l15 * 128 + 16 * l4) ^ swzm));
    pf[1] = *(const short8*)(Pw + ((l15 * 128 + 16 * l4 + 64) ^ swzm));
  };

  stage(0, 0);
  __syncthreads();
  int cur = 0;

  for (int st = 0; st < NST; ++st) {
    if (st + 1 < NST) stage(cur ^ 1, st + 1);

    const char* Kl = Kb0 + cur * 16384;
    const char* Vl = Vb0 + cur * 16384;

    // ---- QK^T (swapped): S^T[kv][q]; kc outer so dependent MFMAs are 8 apart ----
    f32x4 S0[4], S1[4];
#pragma unroll
    for (int ct = 0; ct < 4; ++ct) { S0[ct] = (f32x4){0,0,0,0}; S1[ct] = (f32x4){0,0,0,0}; }
    __builtin_amdgcn_s_setprio(1);
#pragma unroll
    for (int kc = 0; kc < 4; ++kc) {
#pragma unroll
      for (int ct = 0; ct < 4; ++ct) {
        int kr = 16 * ct + l15;
        short8 af = *(const short8*)(Kl + ((kr * 256 + 16 * l4 + 64 * kc) ^ ((kr & 7) << 4)));
        S0[ct] = __builtin_amdgcn_mfma_f32_16x16x32_bf16(af, qf0[kc], S0[ct], 0, 0, 0);
        S1[ct] = __builtin_amdgcn_mfma_f32_16x16x32_bf16(af, qf1[kc], S1[ct], 0, 0, 0);
      }
    }
    __builtin_amdgcn_s_setprio(0);

    short8 pf0[2], pf1[2];
    softmax_prep(S0, m0, l0, O0, pf0);
    softmax_prep(S1, m1, l1, O1, pf1);

    // ---- PV (swapped): O^T[h][q]; kc2 outer for independent chains ----
    __builtin_amdgcn_s_setprio(1);
#pragma unroll
    for (int kc2 = 0; kc2 < 2; ++kc2) {
#pragma unroll
      for (int ct2 = 0; ct2 < 8; ++ct2) {
        int hr = 16 * ct2 + l15;
        short8 vf = *(const short8*)(Vl + ((hr * 128 + 16 * l4 + 64 * kc2) ^ ((hr & 7) << 4)));
        O0[ct2] = __builtin_amdgcn_mfma_f32_16x16x32_bf16(vf, pf0[kc2], O0[ct2], 0, 0, 0);
        O1[ct2] = __builtin_amdgcn_mfma_f32_16x16x32_bf16(vf, pf1[kc2], O1[ct2], 0, 0, 0);
      }
    }
    __builtin_amdgcn_s_setprio(0);

    __syncthreads();
    cur ^= 1;
  }

  // ---- epilogue: O^T -> LDS transpose -> coalesced partial store + m/l ----
#pragma unroll
  for (int ct2 = 0; ct2 < 8; ++ct2) {
    int q0 = wave * 32 + l15;
    *(f32x4*)(smem + q0 * 512 + ((64 * ct2 + 16 * l4) ^ ((q0 & 7) << 4))) = O0[ct2];
    int q1 = q0 + 16;
    *(f32x4*)(smem + q1 * 512 + ((64 * ct2 + 16 * l4) ^ ((q1 & 7) << 4))) = O1[ct2];
  }
  if (l4 == 0) {
    size_t r0 = ((size_t)z * B_ + b) * N_ + qg0 + l15;
    mlpart[2 * r0] = m0;
    mlpart[2 * r0 + 1] = l0;
    mlpart[2 * (r0 + 16)] = m1;
    mlpart[2 * (r0 + 16) + 1] = l1;
  }
  __syncthreads();
  float* od = opart + (((size_t)z * B_ + b) * N_ + (size_t)x * QT) * H_;
#pragma unroll
  for (int i = 0; i < 16; ++i) {
    int off = (tid + 256 * i) * 16;
    int q = off >> 9, colb = off & 511;
    f32x4 val = *(const f32x4*)(smem + q * 512 + (colb ^ ((q & 7) << 4)));
    *(f32x4*)((char*)od + (size_t)q * 512 + colb) = val;
  }
}

// ---------------- combine the KS kv-split partials ----------------
template <int KS>
__global__ void combine_k(const float* __restrict__ opart, const float* __restrict__ mlpart,
                          float* __restrict__ out) {
  const int t = threadIdx.x;
  size_t row = (size_t)blockIdx.x * 8 + (t >> 5);
  int hc = (t & 31) * 4;
  float mz[KS], lz[KS];
  float mi = -__builtin_inff();
#pragma unroll
  for (int z = 0; z < KS; ++z) {
    size_t r = (size_t)z * B_ * N_ + row;
    mz[z] = mlpart[2 * r];
    lz[z] = mlpart[2 * r + 1];
    mi = fmaxf(mi, mz[z]);
  }
  float lsum = 0.f;
  float az[KS];
#pragma unroll
  for (int z = 0; z < KS; ++z) {
    az[z] = __builtin_amdgcn_exp2f(mz[z] - mi);
    lsum += az[z] * lz[z];
  }
  float rinv = 1.f / lsum;
  f32x4 acc = (f32x4){0, 0, 0, 0};
#pragma unroll
  for (int z = 0; z < KS; ++z) {
    f32x4 oz = *(const f32x4*)(opart + (size_t)z * B_ * N_ * H_ + row * H_ + hc);
    acc = acc + oz * (az[z] * rinv);
  }
  *(f32x4*)(out + row * H_ + hc) = acc;
}

// ================= R2 fallback path (minimal ws) =================
constexpr int FB_QTILE = 64;
constexpr int FB_KVSTEP = 128;
constexpr int FB_KVHALF = 64;
constexpr int FB_NTH = 512;
constexpr int FB_NSTEPS = N_ / FB_KVSTEP;

__global__ __launch_bounds__(FB_NTH, 2)
void fattn_fast(const unsigned short* __restrict__ qws,
                const unsigned short* __restrict__ kws,
                const unsigned short* __restrict__ vtws,
                float* __restrict__ out) {
  __shared__ unsigned short Kbuf[2][FB_KVSTEP * H_];
  __shared__ unsigned short Vbuf[2][H_ * FB_KVSTEP];
  __shared__ unsigned short Plds[8][16 * FB_KVHALF];
  __shared__ float MLlds[4][16][2];

  const int tid = threadIdx.x;
  const int wave = tid >> 6;
  const int lane = tid & 63;
  const int l15 = lane & 15;
  const int l4 = lane >> 4;
  const int sub = wave & 3;
  const int grp = wave >> 2;

  const int b = blockIdx.y;
  const int qbase = blockIdx.x * FB_QTILE;

  const unsigned short* qp = qws + ((size_t)b * N_ + qbase + sub * 16 + l15) * H_;
  short8 qfrag[4];
#pragma unroll
  for (int kc = 0; kc < 4; ++kc)
    qfrag[kc] = *(const short8*)(qp + 8 * l4 + 32 * kc);

  f32x4 Oacc[8];
#pragma unroll
  for (int i = 0; i < 8; ++i) Oacc[i] = (f32x4){0.f, 0.f, 0.f, 0.f};
  float mrun[4], lrun[4];
#pragma unroll
  for (int r = 0; r < 4; ++r) { mrun[r] = -__builtin_inff(); lrun[r] = 0.f; }

  const char* kbase = (const char*)(kws + (size_t)b * N_ * H_);
  const char* vbase = (const char*)(vtws + (size_t)b * H_ * N_);
  const int kvbase = grp * FB_KVHALF;
  char* pbase = (char*)Plds[wave];

  auto stage = [&](int buf, int step) {
    const char* ktile = kbase + (size_t)step * FB_KVSTEP * H_ * 2;
#pragma unroll
    for (int i = 0; i < 4; ++i) {
      int chunk = wave * 4 + i;
      int off = chunk * 1024 + lane * 16;
      int row = off >> 8, col = off & 255;
      gl_lds16(ktile + row * 256 + (col ^ ((row & 7) << 4)),
               (char*)Kbuf[buf] + chunk * 1024);
    }
#pragma unroll
    for (int i = 0; i < 4; ++i) {
      int chunk = wave * 4 + i;
      int h = chunk * 4 + (lane >> 4);
      int colb = (lane & 15) * 16;
      gl_lds16(vbase + (size_t)h * (N_ * 2) + (size_t)step * 256 + (colb ^ ((h & 7) << 4)),
               (char*)Vbuf[buf] + chunk * 1024);
    }
  };

  int cur = 0;
  stage(0, 0);
  __syncthreads();

  for (int step = 0; step < FB_NSTEPS; ++step) {
    if (step + 1 < FB_NSTEPS) stage(cur ^ 1, step + 1);

    const char* Kl = (const char*)Kbuf[cur];
    const char* Vl = (const char*)Vbuf[cur];

    f32x4 S[4];
#pragma unroll
    for (int ct = 0; ct < 4; ++ct) S[ct] = (f32x4){0.f, 0.f, 0.f, 0.f};
#pragma unroll
    for (int ct = 0; ct < 4; ++ct) {
      int kvrow = kvbase + ct * 16 + l15;
#pragma unroll
      for (int kc = 0; kc < 4; ++kc) {
        short8 bfrag = *(const short8*)(Kl +
            swz(kvrow * 256 + (8 * l4 + 32 * kc) * 2, kvrow));
        S[ct] = __builtin_amdgcn_mfma_f32_16x16x32_bf16(qfrag[kc], bfrag, S[ct], 0, 0, 0);
      }
    }

    float mnew[4];
#pragma unroll
    for (int r = 0; r < 4; ++r) {
      float mx = fmaxf(fmaxf(S[0][r], S[1][r]), fmaxf(S[2][r], S[3][r]));
      mx = fmaxf(mx, __shfl_xor(mx, 1));
      mx = fmaxf(mx, __shfl_xor(mx, 2));
      mx = fmaxf(mx, __shfl_xor(mx, 4));
      mx = fmaxf(mx, __shfl_xor(mx, 8));
      mnew[r] = mx;
    }
    float alpha[4];
#pragma unroll
    for (int r = 0; r < 4; ++r) {
      float mi = fmaxf(mrun[r], mnew[r]);
      alpha[r] = __builtin_amdgcn_exp2f(mrun[r] - mi);
      mrun[r] = mi;
    }
    float rsum[4] = {0.f, 0.f, 0.f, 0.f};
    unsigned short pb[4][4];
#pragma unroll
    for (int ct = 0; ct < 4; ++ct)
#pragma unroll
      for (int r = 0; r < 4; ++r) {
        float pv = __builtin_amdgcn_exp2f(S[ct][r] - mrun[r]);
        rsum[r] += pv;
        pb[ct][r] = f2bf(pv);
      }
#pragma unroll
    for (int r = 0; r < 4; ++r) {
      float s = rsum[r];
      s += __shfl_xor(s, 1); s += __shfl_xor(s, 2);
      s += __shfl_xor(s, 4); s += __shfl_xor(s, 8);
      lrun[r] = lrun[r] * alpha[r] + s;
    }
#pragma unroll
    for (int ct2 = 0; ct2 < 8; ++ct2)
#pragma unroll
      for (int r = 0; r < 4; ++r) Oacc[ct2][r] *= alpha[r];

#pragma unroll
    for (int ct = 0; ct < 4; ++ct)
#pragma unroll
      for (int r = 0; r < 4; ++r) {
        int qrow = 4 * l4 + r;
        int kv = l15 + 16 * ct;
        *(unsigned short*)(pbase + swz(qrow * 128 + kv * 2, qrow)) = pb[ct][r];
      }

#pragma unroll
    for (int kc2 = 0; kc2 < 2; ++kc2) {
      short8 afrag = *(const short8*)(pbase +
          swz(l15 * 128 + (8 * l4 + 32 * kc2) * 2, l15));
#pragma unroll
      for (int ct2 = 0; ct2 < 8; ++ct2) {
        int h = l15 + 16 * ct2;
        short8 bfrag = *(const short8*)(Vl +
            swz(h * 256 + (kvbase + 8 * l4 + 32 * kc2) * 2, h));
        Oacc[ct2] = __builtin_amdgcn_mfma_f32_16x16x32_bf16(afrag, bfrag, Oacc[ct2], 0, 0, 0);
      }
    }

    __syncthreads();
    cur ^= 1;
  }

  __syncthreads();
  float* mergeO = (float*)Kbuf;
  if (grp == 1) {
#pragma unroll
    for (int ct2 = 0; ct2 < 8; ++ct2)
#pragma unroll
      for (int r = 0; r < 4; ++r) {
        int qrow = 4 * l4 + r, h = l15 + 16 * ct2;
        mergeO[(sub * 16 + qrow) * H_ + h] = Oacc[ct2][r];
      }
    if (l15 == 0) {
#pragma unroll
      for (int r = 0; r < 4; ++r) {
        int qrow = 4 * l4 + r;
        MLlds[sub][qrow][0] = mrun[r];
        MLlds[sub][qrow][1] = lrun[r];
      }
    }
  }
  __syncthreads();
  if (grp == 0) {
    float aA[4], aB[4], rl[4];
#pragma unroll
    for (int r = 0; r < 4; ++r) {
      int qrow = 4 * l4 + r;
      float mB = MLlds[sub][qrow][0], lB = MLlds[sub][qrow][1];
      float mi = fmaxf(mrun[r], mB);
      aA[r] = __builtin_amdgcn_exp2f(mrun[r] - mi);
      aB[r] = __builtin_amdgcn_exp2f(mB - mi);
      rl[r] = 1.f / (lrun[r] * aA[r] + lB * aB[r]);
    }
    float* outp = out + ((size_t)b * N_ + qbase + sub * 16) * H_;
#pragma unroll
    for (int ct2 = 0; ct2 < 8; ++ct2)
#pragma unroll
      for (int r = 0; r < 4; ++r) {
        int qrow = 4 * l4 + r, h = l15 + 16 * ct2;
        float ob = mergeO[(sub * 16 + qrow) * H_ + h];
        outp[(size_t)qrow * H_ + h] = (Oacc[ct2][r] * aA[r] + ob * aB[r]) * rl[r];
      }
  }
}

extern "C" void kernel_launch(void* const* d_in, const int* in_sizes, int n_in,
                              void* d_out, int out_size, void* d_ws, size_t ws_size,
                              hipStream_t stream) {
  const float* q = (const float*)d_in[0];
  const float* k = (const float*)d_in[1];
  const float* v = (const float*)d_in[2];
  float* out = (float*)d_out;

  auto need = [](int ks) {
    return 3 * TSB + (size_t)ks * ELEMS * 4 + (size_t)ks * B_ * N_ * 2 * 4;
  };

  if (ws_size >= need(4)) {
    unsigned short* qb = (unsigned short*)d_ws;
    unsigned short* kb = qb + ELEMS;
    unsigned short* vt = kb + ELEMS;
    float* opart = (float*)((char*)d_ws + 3 * TSB);
    float* mlpart = opart + (size_t)4 * ELEMS;
    conv_qk<<<dim3((unsigned)(ELEMS / 8 / 256)), dim3(256), 0, stream>>>(q, k, qb, kb);
    conv_vt<<<dim3(N_ / 64, H_ / 64, B_), dim3(256), 0, stream>>>(v, vt);
    fattn_v5<4><<<dim3(512), dim3(NTH), 0, stream>>>(qb, kb, vt, opart, mlpart);
    combine_k<4><<<dim3(B_ * N_ / 8), dim3(256), 0, stream>>>(opart, mlpart, out);
  } else if (ws_size >= need(2)) {
    unsigned short* qb = (unsigned short*)d_ws;
    unsigned short* kb = qb + ELEMS;
    unsigned short* vt = kb + ELEMS;
    float* opart = (float*)((char*)d_ws + 3 * TSB);
    float* mlpart = opart + (size_t)2 * ELEMS;
    conv_qk<<<dim3((unsigned)(ELEMS / 8 / 256)), dim3(256), 0, stream>>>(q, k, qb, kb);
    conv_vt<<<dim3(N_ / 64, H_ / 64, B_), dim3(256), 0, stream>>>(v, vt);
    fattn_v5<2><<<dim3(256), dim3(NTH), 0, stream>>>(qb, kb, vt, opart, mlpart);
    combine_k<2><<<dim3(B_ * N_ / 8), dim3(256), 0, stream>>>(opart, mlpart, out);
  } else if (ws_size >= 3 * TSB) {
    unsigned short* qb = (unsigned short*)d_ws;
    unsigned short* kb = qb + ELEMS;
    unsigned short* vt = kb + ELEMS;
    conv_qk<<<dim3((unsigned)(ELEMS / 8 / 256)), dim3(256), 0, stream>>>(q, k, qb, kb);
    conv_vt<<<dim3(N_ / 64, H_ / 64, B_), dim3(256), 0, stream>>>(v, vt);
    fattn_fast<<<dim3(N_ / FB_QTILE, B_), dim3(FB_NTH), 0, stream>>>(qb, kb, vt, out);
  }
}